// Round 2
// 645.194 us; speedup vs baseline: 1.0472x; 1.0472x over previous
//
#include <hip/hip_runtime.h>
#include <hip/hip_bf16.h>
#include <math.h>
#include <stdint.h>

// ---------------------------------------------------------------------------
// SceneSegmenter Round 6 (resubmit — prior bench hit GPUAcquisitionTimeout).
//  - qkv_pack: one-time fp32->bf16 pack of proj outputs (Q scaled, K tile-
//    contiguous, V transposed + key-permuted) so attention staging is pure
//    16B copies with no cvt VALU and no scalar transpose writes.
//  - attn_bf16_split: split-K flash reading the packed buffers.
//  - gemm_bout_head: bout GEMM with fused bpW-dot + sigmoid epilogue.
// Layouts: token-major activations (S, B, D) flat, row = s*8+b.
// ---------------------------------------------------------------------------

#define DEV static __device__ __forceinline__

typedef __attribute__((ext_vector_type(8))) short bf16x8;   // 8 bf16 (4 VGPRs)
typedef __attribute__((ext_vector_type(4))) float f32x4;    // MFMA C/D

DEV uint32_t pk2bf(float a, float b) {       // packed fp32x2 -> bf16x2 (RNE)
  __hip_bfloat162 h = __float22bfloat162_rn(make_float2(a, b));
  return *(uint32_t*)&h;
}
DEV uint2 cvt4(float4 f) {                   // 4 fp32 -> 4 bf16
  return make_uint2(pk2bf(f.x, f.y), pk2bf(f.z, f.w));
}

// ---------------------------------------------------------------------------
// bf16 MFMA GEMM, BM=64 x BN=128, BK=64, 256 thr = 4 waves (each wave: 64
// rows x 32 cols). K % 64 == 0. Fragment layouts verified m89/m91.
// remap=1: out row r = (m & 2047)*8 + (m >> 11)   ((B,S)->(S,B))
// ---------------------------------------------------------------------------
__global__ __launch_bounds__(256) void gemm_mfma64(
    const float* __restrict__ A, int lda,
    const float* __restrict__ W,
    const float* __restrict__ bias,
    float* __restrict__ C, int ldc,
    int M, int K, int relu, int remap)
{
  __shared__ __align__(16) uint16_t As[64 * 72];
  __shared__ __align__(16) uint16_t Ws[128 * 72];

  const int t  = threadIdx.x;
  const int m0 = blockIdx.x * 64;
  const int n0 = blockIdx.y * 128;
  const int w  = t >> 6, l = t & 63;
  const int ln = l & 15, qd = l >> 4;

  f32x4 acc[4][2];
#pragma unroll
  for (int i = 0; i < 4; ++i) { acc[i][0] = (f32x4){0,0,0,0}; acc[i][1] = (f32x4){0,0,0,0}; }

  const int rr = t >> 4;          // 0..15
  const int cl = (t & 15) * 4;    // float col within 64-chunk

  for (int k0 = 0; k0 < K; k0 += 64) {
    __syncthreads();
#pragma unroll
    for (int i = 0; i < 4; ++i) {           // A tile: 64 rows
      int m = m0 + rr + 16 * i;
      int mc = m < M ? m : M - 1;
      float4 f = *(const float4*)(A + (size_t)mc * lda + k0 + cl);
      *(uint2*)(As + (size_t)(rr + 16 * i) * 72 + cl) = cvt4(f);
    }
#pragma unroll
    for (int i = 0; i < 8; ++i) {           // W tile: 128 rows
      int n = n0 + rr + 16 * i;
      float4 f = *(const float4*)(W + (size_t)n * K + k0 + cl);
      *(uint2*)(Ws + (size_t)(rr + 16 * i) * 72 + cl) = cvt4(f);
    }
    __syncthreads();
#pragma unroll
    for (int ks = 0; ks < 2; ++ks) {
      bf16x8 af[4], bf[2];
#pragma unroll
      for (int mf = 0; mf < 4; ++mf)
        af[mf] = *(const bf16x8*)(As + (size_t)(mf * 16 + ln) * 72 + ks * 32 + qd * 8);
#pragma unroll
      for (int nf = 0; nf < 2; ++nf)
        bf[nf] = *(const bf16x8*)(Ws + (size_t)(w * 32 + nf * 16 + ln) * 72 + ks * 32 + qd * 8);
#pragma unroll
      for (int mf = 0; mf < 4; ++mf)
#pragma unroll
        for (int nf = 0; nf < 2; ++nf)
          acc[mf][nf] = __builtin_amdgcn_mfma_f32_16x16x32_bf16(af[mf], bf[nf], acc[mf][nf], 0, 0, 0);
    }
  }

#pragma unroll
  for (int mf = 0; mf < 4; ++mf) {
#pragma unroll
    for (int r = 0; r < 4; ++r) {
      int m = m0 + mf * 16 + qd * 4 + r;
      if (m < M) {
        size_t ro = remap ? (size_t)((m & 2047) * 8 + (m >> 11)) : (size_t)m;
#pragma unroll
        for (int nf = 0; nf < 2; ++nf) {
          int n = n0 + w * 32 + nf * 16 + ln;
          float v = acc[mf][nf][r] + bias[n];
          if (relu) v = fmaxf(v, 0.f);
          C[ro * (size_t)ldc + n] = v;
        }
      }
    }
  }
}

// ---------------------------------------------------------------------------
// Fused 4-segment feats GEMM: blockIdx.y = segment, BM=64.
// feats[16384 x 512], segment n-cols at seg*128. 1024 blocks total.
// ---------------------------------------------------------------------------
__global__ __launch_bounds__(256) void gemm_feats64(
    const float* __restrict__ x,
    const float* __restrict__ pW, const float* __restrict__ pb,
    const float* __restrict__ cW, const float* __restrict__ cb,
    const float* __restrict__ aW, const float* __restrict__ ab,
    const float* __restrict__ uW, const float* __restrict__ ub,
    float* __restrict__ feats)
{
  __shared__ __align__(16) uint16_t As[64 * 72];
  __shared__ __align__(16) uint16_t Ws[128 * 72];

  const int seg = blockIdx.y;
  const float* W; const float* bias; int kbase, Kseg;
  if (seg == 0)      { W = pW; bias = pb; kbase = 0;    Kseg = 2048; }
  else if (seg == 1) { W = cW; bias = cb; kbase = 2048; Kseg = 512; }
  else if (seg == 2) { W = aW; bias = ab; kbase = 2560; Kseg = 512; }
  else               { W = uW; bias = ub; kbase = 3072; Kseg = 512; }

  const int t  = threadIdx.x;
  const int m0 = blockIdx.x * 64;
  const int w  = t >> 6, l = t & 63;
  const int ln = l & 15, qd = l >> 4;

  f32x4 acc[4][2];
#pragma unroll
  for (int i = 0; i < 4; ++i) { acc[i][0] = (f32x4){0,0,0,0}; acc[i][1] = (f32x4){0,0,0,0}; }

  const int rr = t >> 4;
  const int cl = (t & 15) * 4;

  for (int k0 = 0; k0 < Kseg; k0 += 64) {
    __syncthreads();
#pragma unroll
    for (int i = 0; i < 4; ++i) {
      int m = m0 + rr + 16 * i;
      float4 f = *(const float4*)(x + (size_t)m * 3584 + kbase + k0 + cl);
      *(uint2*)(As + (size_t)(rr + 16 * i) * 72 + cl) = cvt4(f);
    }
#pragma unroll
    for (int i = 0; i < 8; ++i) {
      int n = rr + 16 * i;
      float4 f = *(const float4*)(W + (size_t)n * Kseg + k0 + cl);
      *(uint2*)(Ws + (size_t)(rr + 16 * i) * 72 + cl) = cvt4(f);
    }
    __syncthreads();
#pragma unroll
    for (int ks = 0; ks < 2; ++ks) {
      bf16x8 af[4], bf[2];
#pragma unroll
      for (int mf = 0; mf < 4; ++mf)
        af[mf] = *(const bf16x8*)(As + (size_t)(mf * 16 + ln) * 72 + ks * 32 + qd * 8);
#pragma unroll
      for (int nf = 0; nf < 2; ++nf)
        bf[nf] = *(const bf16x8*)(Ws + (size_t)(w * 32 + nf * 16 + ln) * 72 + ks * 32 + qd * 8);
#pragma unroll
      for (int mf = 0; mf < 4; ++mf)
#pragma unroll
        for (int nf = 0; nf < 2; ++nf)
          acc[mf][nf] = __builtin_amdgcn_mfma_f32_16x16x32_bf16(af[mf], bf[nf], acc[mf][nf], 0, 0, 0);
    }
  }

#pragma unroll
  for (int mf = 0; mf < 4; ++mf) {
#pragma unroll
    for (int r = 0; r < 4; ++r) {
      int m = m0 + mf * 16 + qd * 4 + r;
#pragma unroll
      for (int nf = 0; nf < 2; ++nf) {
        int n = w * 32 + nf * 16 + ln;
        float v = fmaxf(acc[mf][nf][r] + bias[n], 0.f);
        feats[(size_t)m * 512 + seg * 128 + n] = v;
      }
    }
  }
}

// ---------------------------------------------------------------------------
// becat MFMA GEMM, BM=64: b0[16376 x 128] = relu(cat(left,right) @ beW^T + b).
// A rows synthesized from csum (S,B,128); K=256. 256 blocks.
// ---------------------------------------------------------------------------
__global__ __launch_bounds__(256) void gemm_becat64(
    const float* __restrict__ csum,
    const float* __restrict__ W, const float* __restrict__ bias,
    float* __restrict__ C)
{
  __shared__ __align__(16) uint16_t As[64 * 72];
  __shared__ __align__(16) uint16_t Ws[128 * 72];

  const int M = 16376, K = 256;
  const int t  = threadIdx.x;
  const int m0 = blockIdx.x * 64;
  const int w  = t >> 6, l = t & 63;
  const int ln = l & 15, qd = l >> 4;

  f32x4 acc[4][2];
#pragma unroll
  for (int i = 0; i < 4; ++i) { acc[i][0] = (f32x4){0,0,0,0}; acc[i][1] = (f32x4){0,0,0,0}; }

  const int rr = t >> 4;
  const int cl = (t & 15) * 4;

  for (int k0 = 0; k0 < K; k0 += 64) {
    __syncthreads();
#pragma unroll
    for (int i = 0; i < 4; ++i) {
      int m = m0 + rr + 16 * i;
      int mc = m < M ? m : M - 1;
      int j = mc >> 3, bb = mc & 7;
      int kk = k0 + cl;
      float4 f;
      if (kk < 128) {
        float4 v = *(const float4*)(csum + (size_t)mc * 128 + kk);
        float s = 1.f / (float)(j + 1);
        f = make_float4(v.x * s, v.y * s, v.z * s, v.w * s);
      } else {
        int d = kk - 128;
        float4 c0 = *(const float4*)(csum + (size_t)mc * 128 + d);
        float4 ct = *(const float4*)(csum + (size_t)(16376 + bb) * 128 + d);
        float s = 1.f / (float)(2047 - j);
        f = make_float4((ct.x - c0.x) * s, (ct.y - c0.y) * s,
                        (ct.z - c0.z) * s, (ct.w - c0.w) * s);
      }
      *(uint2*)(As + (size_t)(rr + 16 * i) * 72 + cl) = cvt4(f);
    }
#pragma unroll
    for (int i = 0; i < 8; ++i) {
      int n = rr + 16 * i;
      float4 f = *(const float4*)(W + (size_t)n * K + k0 + cl);
      *(uint2*)(Ws + (size_t)(rr + 16 * i) * 72 + cl) = cvt4(f);
    }
    __syncthreads();
#pragma unroll
    for (int ks = 0; ks < 2; ++ks) {
      bf16x8 af[4], bf[2];
#pragma unroll
      for (int mf = 0; mf < 4; ++mf)
        af[mf] = *(const bf16x8*)(As + (size_t)(mf * 16 + ln) * 72 + ks * 32 + qd * 8);
#pragma unroll
      for (int nf = 0; nf < 2; ++nf)
        bf[nf] = *(const bf16x8*)(Ws + (size_t)(w * 32 + nf * 16 + ln) * 72 + ks * 32 + qd * 8);
#pragma unroll
      for (int mf = 0; mf < 4; ++mf)
#pragma unroll
        for (int nf = 0; nf < 2; ++nf)
          acc[mf][nf] = __builtin_amdgcn_mfma_f32_16x16x32_bf16(af[mf], bf[nf], acc[mf][nf], 0, 0, 0);
    }
  }

#pragma unroll
  for (int mf = 0; mf < 4; ++mf) {
#pragma unroll
    for (int r = 0; r < 4; ++r) {
      int m = m0 + mf * 16 + qd * 4 + r;
      if (m < M) {
#pragma unroll
        for (int nf = 0; nf < 2; ++nf) {
          int n = w * 32 + nf * 16 + ln;
          C[(size_t)m * 128 + n] = fmaxf(acc[mf][nf][r] + bias[n], 0.f);
        }
      }
    }
  }
}

// ---------------------------------------------------------------------------
// qkv_pack: proj (M x 384 fp32, token-major) ->
//   Qb  [16384][128] bf16, pre-scaled by 1/sqrt(128), token-major
//   Kb  [b][tile32][key64][128] bf16 (tile = contiguous 16KB)
//   Vtb [b][tile32][d128][key64] bf16, keys permuted within tile:
//        uint16 pos p <-> key = 16*(p&3) + (p>>2)  (matches PbL pack order)
// Invalid keys (s >= Slen) are zeroed (K,V); Q clamps source row.
// grid (32, 8), 256 threads.
// ---------------------------------------------------------------------------
__global__ __launch_bounds__(256) void qkv_pack(
    const float* __restrict__ proj,
    uint16_t* __restrict__ Qb, uint16_t* __restrict__ Kb,
    uint16_t* __restrict__ Vtb, int Slen)
{
  __shared__ __align__(16) float Vs[64][132];

  const int kt = blockIdx.x, b = blockIdx.y;
  const int t  = threadIdx.x;
  const int sl = t >> 2;             // 0..63 local key/token
  const int cg = (t & 3) * 32;       // 32-col group
  const int s  = kt * 64 + sl;
  const int valid = s < Slen;
  const int sc = valid ? s : Slen - 1;
  const float* src = proj + ((size_t)sc * 8 + b) * 384;
  const float scl = 0.08838834764831845f;   // 1/sqrt(128)

  { // Q (scaled), token-major row s*8+b
    uint16_t* dq = Qb + ((size_t)s * 8 + b) * 128 + cg;
#pragma unroll
    for (int i = 0; i < 4; ++i) {
      float4 f0 = *(const float4*)(src + cg + i * 8);
      float4 f1 = *(const float4*)(src + cg + i * 8 + 4);
      uint2 u0 = cvt4(make_float4(f0.x * scl, f0.y * scl, f0.z * scl, f0.w * scl));
      uint2 u1 = cvt4(make_float4(f1.x * scl, f1.y * scl, f1.z * scl, f1.w * scl));
      *(uint4*)(dq + i * 8) = make_uint4(u0.x, u0.y, u1.x, u1.y);
    }
  }
  { // K, tile-contiguous
    uint16_t* dk = Kb + (((size_t)b * 32 + kt) * 64 + sl) * 128 + cg;
#pragma unroll
    for (int i = 0; i < 4; ++i) {
      uint4 u;
      if (valid) {
        float4 f0 = *(const float4*)(src + 128 + cg + i * 8);
        float4 f1 = *(const float4*)(src + 128 + cg + i * 8 + 4);
        uint2 u0 = cvt4(f0), u1 = cvt4(f1);
        u = make_uint4(u0.x, u0.y, u1.x, u1.y);
      } else u = make_uint4(0u, 0u, 0u, 0u);
      *(uint4*)(dk + i * 8) = u;
    }
  }
  // V -> LDS fp32 (row-major [key][d])
#pragma unroll
  for (int i = 0; i < 8; ++i) {
    float4 f = valid ? *(const float4*)(src + 256 + cg + i * 4)
                     : make_float4(0.f, 0.f, 0.f, 0.f);
    *(float4*)(&Vs[sl][cg + i * 4]) = f;
  }
  __syncthreads();
  // transpose + permute-pack, 128 threads (one per d)
  if (t < 128) {
    const int d = t;
    union { uint32_t w[32]; uint4 q[8]; } o;
#pragma unroll
    for (int k0o = 0; k0o < 16; ++k0o) {
      o.w[k0o * 2]     = pk2bf(Vs[k0o][d],      Vs[k0o + 16][d]);
      o.w[k0o * 2 + 1] = pk2bf(Vs[k0o + 32][d], Vs[k0o + 48][d]);
    }
    uint16_t* dv = Vtb + (((size_t)b * 32 + kt) * 128 + d) * 64;
#pragma unroll
    for (int i = 0; i < 8; ++i)
      *(uint4*)(dv + i * 8) = o.q[i];
  }
}

// ---------------------------------------------------------------------------
// Split-K flash attention over packed bf16 Q/K/Vt. blockIdx.z = split
// (keys [z*1024, end)). Stores UNNORMALIZED O partials + (m, l) per row.
// Staging is pure 16B copies: no cvt VALU, no scalar transpose writes.
// ---------------------------------------------------------------------------
__global__ __launch_bounds__(256) void attn_bf16_split(
    const uint16_t* __restrict__ Qb, const uint16_t* __restrict__ Kb,
    const uint16_t* __restrict__ Vtb,
    float* __restrict__ Opart, float* __restrict__ ml, int Slen)
{
  __shared__ __align__(16) uint16_t KsL[64 * 136];     // [key][k], pitch 136
  __shared__ __align__(16) uint16_t VtL[128 * 72];     // [d][k'],  pitch 72
  __shared__ __align__(16) uint16_t PbL[4][16 * 72];   // per-wave [q][k']

  const int t  = threadIdx.x;
  const int b  = blockIdx.y;
  const int q0 = blockIdx.x * 64;
  const int split = blockIdx.z;
  const int kbeg = split * 1024;
  const int kend = min(Slen, kbeg + 1024);
  const int w  = t >> 6;
  const int l  = t & 63;
  const int ln = l & 15;
  const int qd = l >> 4;

  bf16x8 qf[4];
  {
    int qrow = q0 + w * 16 + ln;
    int qc = qrow < Slen ? qrow : Slen - 1;
    const uint16_t* qp = Qb + ((size_t)qc * 8 + b) * 128 + qd * 8;
#pragma unroll
    for (int ks = 0; ks < 4; ++ks) qf[ks] = *(const bf16x8*)(qp + ks * 32);
  }

  f32x4 oacc[8];
#pragma unroll
  for (int i = 0; i < 8; ++i) oacc[i] = (f32x4){0.f, 0.f, 0.f, 0.f};
  float mrow[4] = {-INFINITY, -INFINITY, -INFINITY, -INFINITY};
  float lrow[4] = {0.f, 0.f, 0.f, 0.f};

  const int ntiles = (kend - kbeg + 63) >> 6;
  for (int kt = 0; kt < ntiles; ++kt) {
    const int tile = split * 16 + kt;
    __syncthreads();
    { // stage K tile: contiguous 16KB -> padded rows
      const int key = t >> 2, cg = (t & 3) * 32;
      const uint16_t* src = Kb + (((size_t)b * 32 + tile) * 64 + key) * 128 + cg;
      uint16_t* dst = KsL + key * 136 + cg;
#pragma unroll
      for (int i = 0; i < 4; ++i)
        *(bf16x8*)(dst + i * 8) = *(const bf16x8*)(src + i * 8);
    }
    { // stage Vt tile: contiguous 16KB -> padded rows (already transposed+permuted)
      const int d = t >> 1, h = (t & 1) * 32;
      const uint16_t* src = Vtb + (((size_t)b * 32 + tile) * 128 + d) * 64 + h;
      uint16_t* dst = VtL + d * 72 + h;
#pragma unroll
      for (int i = 0; i < 4; ++i)
        *(bf16x8*)(dst + i * 8) = *(const bf16x8*)(src + i * 8);
    }
    __syncthreads();

    f32x4 sc[4];
#pragma unroll
    for (int nf = 0; nf < 4; ++nf) {
      f32x4 acc = (f32x4){0.f, 0.f, 0.f, 0.f};
#pragma unroll
      for (int ks = 0; ks < 4; ++ks) {
        bf16x8 kf = *(const bf16x8*)(KsL + (size_t)(nf * 16 + ln) * 136 + ks * 32 + qd * 8);
        acc = __builtin_amdgcn_mfma_f32_16x16x32_bf16(qf[ks], kf, acc, 0, 0, 0);
      }
      int key = kbeg + kt * 64 + nf * 16 + ln;
      if (key >= kend) { acc[0] = -1e30f; acc[1] = -1e30f; acc[2] = -1e30f; acc[3] = -1e30f; }
      sc[nf] = acc;
    }

    float alphaR[4];
#pragma unroll
    for (int r = 0; r < 4; ++r) {
      float mx = fmaxf(fmaxf(sc[0][r], sc[1][r]), fmaxf(sc[2][r], sc[3][r]));
      mx = fmaxf(mx, __shfl_xor(mx, 1));
      mx = fmaxf(mx, __shfl_xor(mx, 2));
      mx = fmaxf(mx, __shfl_xor(mx, 4));
      mx = fmaxf(mx, __shfl_xor(mx, 8));
      float mNew = fmaxf(mrow[r], mx);
      float p0 = __expf(sc[0][r] - mNew);
      float p1 = __expf(sc[1][r] - mNew);
      float p2 = __expf(sc[2][r] - mNew);
      float p3 = __expf(sc[3][r] - mNew);
      float ps = p0 + p1 + p2 + p3;
      ps += __shfl_xor(ps, 1);
      ps += __shfl_xor(ps, 2);
      ps += __shfl_xor(ps, 4);
      ps += __shfl_xor(ps, 8);
      float alpha = __expf(mrow[r] - mNew);
      mrow[r] = mNew;
      lrow[r] = lrow[r] * alpha + ps;
      alphaR[r] = alpha;
      uint2 pk;
      pk.x = pk2bf(p0, p1);
      pk.y = pk2bf(p2, p3);
      *(uint2*)(PbL[w] + (size_t)(qd * 4 + r) * 72 + ln * 4) = pk;
    }
#pragma unroll
    for (int no = 0; no < 8; ++no) {
#pragma unroll
      for (int r = 0; r < 4; ++r) oacc[no][r] *= alphaR[r];
    }
    __asm__ volatile("s_waitcnt lgkmcnt(0)" ::: "memory");

#pragma unroll
    for (int ks2 = 0; ks2 < 2; ++ks2) {
      bf16x8 af = *(const bf16x8*)(PbL[w] + (size_t)ln * 72 + ks2 * 32 + qd * 8);
#pragma unroll
      for (int no = 0; no < 8; ++no) {
        bf16x8 vf = *(const bf16x8*)(VtL + (size_t)(no * 16 + ln) * 72 + ks2 * 32 + qd * 8);
        oacc[no] = __builtin_amdgcn_mfma_f32_16x16x32_bf16(af, vf, oacc[no], 0, 0, 0);
      }
    }
  }

  // store unnormalized partials + (m, l)
#pragma unroll
  for (int r = 0; r < 4; ++r) {
    int qg = q0 + w * 16 + qd * 4 + r;
    if (qg < Slen) {
      size_t row = (size_t)qg * 8 + b;
      float* dst = Opart + ((size_t)split * 16384 + row) * 128 + ln;
#pragma unroll
      for (int no = 0; no < 8; ++no) dst[no * 16] = oacc[no][r];
      if (ln == 0) {
        ml[((size_t)split * 16384 + row) * 2 + 0] = mrow[r];
        ml[((size_t)split * 16384 + row) * 2 + 1] = lrow[r];
      }
    }
  }
}

// Exact merge of 2 split partials: out = (O0*w0 + O1*w1) / (l0*w0 + l1*w1).
__global__ __launch_bounds__(256) void attn_combine(
    const float* __restrict__ Opart, const float* __restrict__ ml,
    float* __restrict__ out, int rows)
{
  int idx = blockIdx.x * 256 + threadIdx.x;   // one per (row, 4-float group)
  int row = idx >> 5;
  int d   = (idx & 31) * 4;
  if (row >= rows) return;
  float m0 = ml[(size_t)row * 2 + 0],          l0 = ml[(size_t)row * 2 + 1];
  float m1 = ml[((size_t)16384 + row) * 2 + 0], l1 = ml[((size_t)16384 + row) * 2 + 1];
  float M = fmaxf(m0, m1);
  float w0 = __expf(m0 - M), w1 = __expf(m1 - M);
  float inv = 1.f / (l0 * w0 + l1 * w1);
  float4 a = *(const float4*)(Opart + (size_t)row * 128 + d);
  float4 c = *(const float4*)(Opart + ((size_t)16384 + row) * 128 + d);
  float4 o = make_float4((a.x * w0 + c.x * w1) * inv, (a.y * w0 + c.y * w1) * inv,
                         (a.z * w0 + c.z * w1) * inv, (a.w * w0 + c.w * w1) * inv);
  *(float4*)(out + (size_t)row * 128 + d) = o;
}

// ---------------------------------------------------------------------------
// Cumsum over s of e (S,B,128), 32 chunks x 64 rows (256 blocks).
// ---------------------------------------------------------------------------
__global__ void cumsum_p1(const float* __restrict__ e, float* __restrict__ csum,
                          float* __restrict__ part)
{
  int chunk = blockIdx.x, b = blockIdx.y, d = threadIdx.x;
  float run = 0.f;
  int s0 = chunk * 64;
  for (int s = 0; s < 64; ++s) {
    size_t idx = ((size_t)(s0 + s) * 8 + b) * 128 + d;
    run += e[idx];
    csum[idx] = run;
  }
  part[(b * 32 + chunk) * 128 + d] = run;
}

__global__ void cumsum_p2(float* __restrict__ part)
{
  int b = blockIdx.x, d = threadIdx.x;
  float run = 0.f;
  for (int c = 0; c < 32; ++c) {
    float v = part[(b * 32 + c) * 128 + d];
    part[(b * 32 + c) * 128 + d] = run;
    run += v;
  }
}

__global__ void cumsum_p3(float* __restrict__ csum, const float* __restrict__ part)
{
  int chunk = blockIdx.x, b = blockIdx.y, d = threadIdx.x;
  float off = part[(b * 32 + chunk) * 128 + d];
  int s0 = chunk * 64;
  for (int s = 0; s < 64; ++s)
    csum[((size_t)(s0 + s) * 8 + b) * 128 + d] += off;
}

// ---------------------------------------------------------------------------
// bout GEMM (M x 128, K=128) with fused bpW-dot + sigmoid head epilogue.
// out[m] = sigmoid(dot(att2[m]@W^T + bias, bpW) + bpb). 256 blocks.
// ---------------------------------------------------------------------------
__global__ __launch_bounds__(256) void gemm_bout_head(
    const float* __restrict__ A,
    const float* __restrict__ W,
    const float* __restrict__ bias,
    const float* __restrict__ bpW, const float* __restrict__ bpb,
    float* __restrict__ out, int M)
{
  __shared__ __align__(16) uint16_t As[64 * 72];
  __shared__ __align__(16) uint16_t Ws[128 * 72];
  __shared__ float Ct[64][133];

  const int K = 128;
  const int t  = threadIdx.x;
  const int m0 = blockIdx.x * 64;
  const int w  = t >> 6, l = t & 63;
  const int ln = l & 15, qd = l >> 4;

  f32x4 acc[4][2];
#pragma unroll
  for (int i = 0; i < 4; ++i) { acc[i][0] = (f32x4){0,0,0,0}; acc[i][1] = (f32x4){0,0,0,0}; }

  const int rr = t >> 4;
  const int cl = (t & 15) * 4;

  for (int k0 = 0; k0 < K; k0 += 64) {
    __syncthreads();
#pragma unroll
    for (int i = 0; i < 4; ++i) {
      int m = m0 + rr + 16 * i;
      int mc = m < M ? m : M - 1;
      float4 f = *(const float4*)(A + (size_t)mc * 128 + k0 + cl);
      *(uint2*)(As + (size_t)(rr + 16 * i) * 72 + cl) = cvt4(f);
    }
#pragma unroll
    for (int i = 0; i < 8; ++i) {
      int n = rr + 16 * i;
      float4 f = *(const float4*)(W + (size_t)n * K + k0 + cl);
      *(uint2*)(Ws + (size_t)(rr + 16 * i) * 72 + cl) = cvt4(f);
    }
    __syncthreads();
#pragma unroll
    for (int ks = 0; ks < 2; ++ks) {
      bf16x8 af[4], bf[2];
#pragma unroll
      for (int mf = 0; mf < 4; ++mf)
        af[mf] = *(const bf16x8*)(As + (size_t)(mf * 16 + ln) * 72 + ks * 32 + qd * 8);
#pragma unroll
      for (int nf = 0; nf < 2; ++nf)
        bf[nf] = *(const bf16x8*)(Ws + (size_t)(w * 32 + nf * 16 + ln) * 72 + ks * 32 + qd * 8);
#pragma unroll
      for (int mf = 0; mf < 4; ++mf)
#pragma unroll
        for (int nf = 0; nf < 2; ++nf)
          acc[mf][nf] = __builtin_amdgcn_mfma_f32_16x16x32_bf16(af[mf], bf[nf], acc[mf][nf], 0, 0, 0);
    }
  }

  // tile -> LDS (with bias), then fused head reduce
  __syncthreads();
#pragma unroll
  for (int mf = 0; mf < 4; ++mf) {
#pragma unroll
    for (int r = 0; r < 4; ++r) {
      int rowL = mf * 16 + qd * 4 + r;
#pragma unroll
      for (int nf = 0; nf < 2; ++nf) {
        int n = w * 32 + nf * 16 + ln;
        Ct[rowL][n] = acc[mf][nf][r] + bias[n];
      }
    }
  }
  __syncthreads();
  {
    int row = t >> 2, qg = t & 3;
    int m = m0 + row;
    float p = 0.f;
#pragma unroll
    for (int j = 0; j < 32; ++j) {
      int c = qg + j * 4;                 // interleaved -> conflict-free
      p += Ct[row][c] * bpW[c];
    }
    p += __shfl_xor(p, 1);
    p += __shfl_xor(p, 2);
    if (qg == 0 && m < M)
      out[m] = 1.f / (1.f + __expf(-(p + bpb[0])));
  }
}

// ---------------------------------------------------------------------------
extern "C" void kernel_launch(void* const* d_in, const int* in_sizes, int n_in,
                              void* d_out, int out_size, void* d_ws, size_t ws_size,
                              hipStream_t stream)
{
  const float* x       = (const float*)d_in[0];
  const float* pW      = (const float*)d_in[1];
  const float* pb      = (const float*)d_in[2];
  const float* cW      = (const float*)d_in[3];
  const float* cb      = (const float*)d_in[4];
  const float* aW      = (const float*)d_in[5];
  const float* ab      = (const float*)d_in[6];
  const float* uW      = (const float*)d_in[7];
  const float* ub      = (const float*)d_in[8];
  const float* eW      = (const float*)d_in[9];
  const float* eb      = (const float*)d_in[10];
  const float* la_win  = (const float*)d_in[11];
  const float* la_bin  = (const float*)d_in[12];
  const float* la_wout = (const float*)d_in[13];
  const float* la_bout = (const float*)d_in[14];
  const float* beW     = (const float*)d_in[15];
  const float* beb     = (const float*)d_in[16];
  const float* ba_win  = (const float*)d_in[17];
  const float* ba_bin  = (const float*)d_in[18];
  const float* ba_wout = (const float*)d_in[19];
  const float* ba_bout = (const float*)d_in[20];
  const float* bpW     = (const float*)d_in[21];
  const float* bpb     = (const float*)d_in[22];

  float* ws   = (float*)d_ws;
  float* outF = (float*)d_out;

  // Workspace plan (floats), serial aliasing:
  //  [0 .. 6,291,456)     featsB / proj1B / csumB / proj2B
  //  [2,097,152 ..)       partB (32K, coexists only with csum)
  //  [6,291,456 .. 8.39M) att1B / b0B / att2B (2.1M each, serial)
  //  [8,388,608 .. 12.6M) attention partials (2 splits x 2.1M)
  //  [12,582,912 ..)      ml (64K)
  //  [12,648,448 ..)      Qb/Kb/Vtb packed bf16 (3 x 1.05M float-equivalent)
  float* featsB = ws;
  float* e0B    = outF;                // scratch until out-proj 1
  float* proj1B = ws;
  float* att1B  = ws + 6291456;
  float* csumB  = ws;
  float* partB  = ws + 2097152;
  float* b0B    = ws + 6291456;
  float* proj2B = ws;
  float* att2B  = ws + 6291456;
  float* OpartB = ws + 8388608;        // [split][16384][128]
  float* mlB    = ws + 12582912;       // [split][16384][2]
  uint16_t* QbB  = (uint16_t*)(ws + 12648448);
  uint16_t* KbB  = (uint16_t*)(ws + 13697024);
  uint16_t* VtbB = (uint16_t*)(ws + 14745600);

  // 1. feats = relu(segment linears), fused 4-segment, 1024 blocks
  gemm_feats64<<<dim3(256, 4), 256, 0, stream>>>(x, pW, pb, cW, cb, aW, ab, uW, ub, featsB);
  // 2. e0 = relu(feats @ eW^T + eb), remapped (B,S)->(S,B)
  gemm_mfma64<<<dim3(256, 1), 256, 0, stream>>>(featsB, 512, eW, eb, e0B, 128, 16384, 512, 1, 1);
  // 3. proj1 = e0 @ la_win^T + la_bin (768 blocks)
  gemm_mfma64<<<dim3(256, 3), 256, 0, stream>>>(e0B, 128, la_win, la_bin, proj1B, 384, 16384, 128, 0, 0);
  // 4. pack Q/K/Vt bf16, then split-K flash + combine
  qkv_pack<<<dim3(32, 8), 256, 0, stream>>>(proj1B, QbB, KbB, VtbB, 2048);
  attn_bf16_split<<<dim3(32, 8, 2), 256, 0, stream>>>(QbB, KbB, VtbB, OpartB, mlB, 2048);
  attn_combine<<<dim3(2048), 256, 0, stream>>>(OpartB, mlB, att1B, 16384);
  // 5. e = att1 @ la_wout^T + la_bout -> d_out
  gemm_mfma64<<<dim3(256, 1), 256, 0, stream>>>(att1B, 128, la_wout, la_bout, outF, 128, 16384, 128, 0, 0);
  // 6-8. csum
  cumsum_p1<<<dim3(32, 8), 128, 0, stream>>>(outF, csumB, partB);
  cumsum_p2<<<dim3(8), 128, 0, stream>>>(partB);
  cumsum_p3<<<dim3(32, 8), 128, 0, stream>>>(csumB, partB);
  // 9. b0 = relu(cat(left,right) @ beW^T + beb)
  gemm_becat64<<<dim3(256), 256, 0, stream>>>(csumB, beW, beb, b0B);
  // 10. proj2
  gemm_mfma64<<<dim3(256, 3), 256, 0, stream>>>(b0B, 128, ba_win, ba_bin, proj2B, 384, 16376, 128, 0, 0);
  // 11. pack + att2 (Slen = 2047) + combine
  qkv_pack<<<dim3(32, 8), 256, 0, stream>>>(proj2B, QbB, KbB, VtbB, 2047);
  attn_bf16_split<<<dim3(32, 8, 2), 256, 0, stream>>>(QbB, KbB, VtbB, OpartB, mlB, 2047);
  attn_combine<<<dim3(2047), 256, 0, stream>>>(OpartB, mlB, att2B, 16376);
  // 12+13. bout GEMM with fused sigmoid head -> d_out tail
  gemm_bout_head<<<dim3(256), 256, 0, stream>>>(att2B, ba_wout, ba_bout, bpW, bpb, outF + 2097152, 16376);
}

// Round 3
// 553.426 us; speedup vs baseline: 1.2208x; 1.1658x over previous
//
#include <hip/hip_runtime.h>
#include <hip/hip_bf16.h>
#include <math.h>
#include <stdint.h>

// ---------------------------------------------------------------------------
// SceneSegmenter Round 7: bf16-everywhere round.
//  - pack_weights: all GEMM weights -> bf16 once (W staging = pure copies).
//  - All inter-stage activations bf16 (same RNE rounding point as before,
//    moved to the producer epilogue): feats, e0, proj, att, b0.
//  - Attention reads Q,K directly from bf16 proj (Q scaled in-reg);
//    only V needs a pack (transpose) kernel.
//  - 3-way split-K attention: 768 blocks = exactly 3/CU (LDS limit), 12
//    waves/CU for softmax latency hiding.
// Layouts: token-major activations (S, B, D) flat, row = s*8+b.
// ---------------------------------------------------------------------------

#define DEV static __device__ __forceinline__

typedef __attribute__((ext_vector_type(8))) short bf16x8;   // 8 bf16 (4 VGPRs)
typedef __attribute__((ext_vector_type(4))) float f32x4;    // MFMA C/D

DEV uint32_t pk2bf(float a, float b) {       // packed fp32x2 -> bf16x2 (RNE)
  __hip_bfloat162 h = __float22bfloat162_rn(make_float2(a, b));
  return *(uint32_t*)&h;
}
DEV uint2 cvt4(float4 f) {                   // 4 fp32 -> 4 bf16
  return make_uint2(pk2bf(f.x, f.y), pk2bf(f.z, f.w));
}
DEV uint16_t bf1(float a) { return (uint16_t)(pk2bf(a, 0.f) & 0xffffu); }
DEV float frombf(uint16_t h) {
  union { uint32_t u; float f; } v; v.u = ((uint32_t)h) << 16; return v.f;
}

// Weight-pack offsets (halves) inside WB
#define OFF_PW      0u
#define OFF_CW      262144u
#define OFF_AW      327680u
#define OFF_UW      393216u
#define OFF_EW      458752u
#define OFF_LAWIN   524288u
#define OFF_LAWOUT  573440u
#define OFF_BEW     589824u
#define OFF_BAWIN   622592u
#define OFF_BAWOUT  671744u
#define OFF_END     688128u

struct WPtrs { const float* p[10]; };

// ---------------------------------------------------------------------------
// pack_weights: concatenated fp32 weights -> bf16 WB. 672 blocks x 256 thr,
// 4 halves per thread, exact cover of 688128 halves.
// ---------------------------------------------------------------------------
__global__ __launch_bounds__(256) void pack_weights(WPtrs wp, uint16_t* __restrict__ WB)
{
  const uint32_t off[11] = {OFF_PW, OFF_CW, OFF_AW, OFF_UW, OFF_EW, OFF_LAWIN,
                            OFF_LAWOUT, OFF_BEW, OFF_BAWIN, OFF_BAWOUT, OFF_END};
  uint32_t h = (blockIdx.x * 256u + threadIdx.x) * 4u;
  if (h >= OFF_END) return;
  int s = 0;
  while (h >= off[s + 1]) ++s;
  float4 f = *(const float4*)(wp.p[s] + (h - off[s]));
  *(uint2*)(WB + h) = cvt4(f);
}

// ---------------------------------------------------------------------------
// Templated bf16 MFMA GEMM, BM=64 x BN=128, BK=64, 256 thr = 4 waves.
// W always pre-packed bf16. A either bf16 (pure copy) or fp32 (cvt).
// Output either bf16 or fp32. remap: out row = (m & 2047)*8 + (m >> 11).
// ---------------------------------------------------------------------------
template<bool ABF, bool OBF, bool RELU, bool REMAP>
__global__ __launch_bounds__(256) void gemm64(
    const void* __restrict__ Ap, int lda,
    const uint16_t* __restrict__ Wb,
    const float* __restrict__ bias,
    void* __restrict__ Cp, int ldc,
    int M, int K)
{
  __shared__ __align__(16) uint16_t As[64 * 72];
  __shared__ __align__(16) uint16_t Ws[128 * 72];

  const int t  = threadIdx.x;
  const int m0 = blockIdx.x * 64;
  const int n0 = blockIdx.y * 128;
  const int w  = t >> 6, l = t & 63;
  const int ln = l & 15, qd = l >> 4;

  f32x4 acc[4][2];
#pragma unroll
  for (int i = 0; i < 4; ++i) { acc[i][0] = (f32x4){0,0,0,0}; acc[i][1] = (f32x4){0,0,0,0}; }

  const int rr = t >> 4;          // fp32-A path: 16 rows
  const int cl = (t & 15) * 4;
  const int r8 = t >> 3;          // bf16 paths: 32 rows
  const int c8 = (t & 7) * 8;     // half col (16B)

  for (int k0 = 0; k0 < K; k0 += 64) {
    __syncthreads();
    if (ABF) {
      const uint16_t* A = (const uint16_t*)Ap;
#pragma unroll
      for (int i = 0; i < 2; ++i) {
        int m = m0 + r8 + 32 * i;
        int mc = m < M ? m : M - 1;
        *(bf16x8*)(As + (size_t)(r8 + 32 * i) * 72 + c8) =
            *(const bf16x8*)(A + (size_t)mc * lda + k0 + c8);
      }
    } else {
      const float* A = (const float*)Ap;
#pragma unroll
      for (int i = 0; i < 4; ++i) {
        int m = m0 + rr + 16 * i;
        int mc = m < M ? m : M - 1;
        float4 f = *(const float4*)(A + (size_t)mc * lda + k0 + cl);
        *(uint2*)(As + (size_t)(rr + 16 * i) * 72 + cl) = cvt4(f);
      }
    }
#pragma unroll
    for (int i = 0; i < 4; ++i) {           // W tile: 128 rows, pure copy
      int n = r8 + 32 * i;
      *(bf16x8*)(Ws + (size_t)n * 72 + c8) =
          *(const bf16x8*)(Wb + (size_t)(n0 + n) * K + k0 + c8);
    }
    __syncthreads();
#pragma unroll
    for (int ks = 0; ks < 2; ++ks) {
      bf16x8 af[4], bfr[2];
#pragma unroll
      for (int mf = 0; mf < 4; ++mf)
        af[mf] = *(const bf16x8*)(As + (size_t)(mf * 16 + ln) * 72 + ks * 32 + qd * 8);
#pragma unroll
      for (int nf = 0; nf < 2; ++nf)
        bfr[nf] = *(const bf16x8*)(Ws + (size_t)(w * 32 + nf * 16 + ln) * 72 + ks * 32 + qd * 8);
#pragma unroll
      for (int mf = 0; mf < 4; ++mf)
#pragma unroll
        for (int nf = 0; nf < 2; ++nf)
          acc[mf][nf] = __builtin_amdgcn_mfma_f32_16x16x32_bf16(af[mf], bfr[nf], acc[mf][nf], 0, 0, 0);
    }
  }

#pragma unroll
  for (int mf = 0; mf < 4; ++mf) {
#pragma unroll
    for (int r = 0; r < 4; ++r) {
      int m = m0 + mf * 16 + qd * 4 + r;
      if (m < M) {
        size_t ro = REMAP ? (size_t)((m & 2047) * 8 + (m >> 11)) : (size_t)m;
#pragma unroll
        for (int nf = 0; nf < 2; ++nf) {
          int n = n0 + w * 32 + nf * 16 + ln;
          float v = acc[mf][nf][r] + bias[n];
          if (RELU) v = fmaxf(v, 0.f);
          if (OBF) ((uint16_t*)Cp)[ro * (size_t)ldc + n] = bf1(v);
          else     ((float*)Cp)[ro * (size_t)ldc + n] = v;
        }
      }
    }
  }
}

// ---------------------------------------------------------------------------
// Fused 4-segment feats GEMM (A = x fp32, W bf16 pre-packed, out bf16).
// ---------------------------------------------------------------------------
__global__ __launch_bounds__(256) void gemm_feats64(
    const float* __restrict__ x, const uint16_t* __restrict__ WB,
    const float* __restrict__ pb, const float* __restrict__ cb,
    const float* __restrict__ ab, const float* __restrict__ ub,
    uint16_t* __restrict__ feats)
{
  __shared__ __align__(16) uint16_t As[64 * 72];
  __shared__ __align__(16) uint16_t Ws[128 * 72];

  const int seg = blockIdx.y;
  const uint16_t* Wb; const float* bias; int kbase, Kseg;
  if (seg == 0)      { Wb = WB + OFF_PW; bias = pb; kbase = 0;    Kseg = 2048; }
  else if (seg == 1) { Wb = WB + OFF_CW; bias = cb; kbase = 2048; Kseg = 512; }
  else if (seg == 2) { Wb = WB + OFF_AW; bias = ab; kbase = 2560; Kseg = 512; }
  else               { Wb = WB + OFF_UW; bias = ub; kbase = 3072; Kseg = 512; }

  const int t  = threadIdx.x;
  const int m0 = blockIdx.x * 64;
  const int w  = t >> 6, l = t & 63;
  const int ln = l & 15, qd = l >> 4;

  f32x4 acc[4][2];
#pragma unroll
  for (int i = 0; i < 4; ++i) { acc[i][0] = (f32x4){0,0,0,0}; acc[i][1] = (f32x4){0,0,0,0}; }

  const int rr = t >> 4;
  const int cl = (t & 15) * 4;
  const int r8 = t >> 3;
  const int c8 = (t & 7) * 8;

  for (int k0 = 0; k0 < Kseg; k0 += 64) {
    __syncthreads();
#pragma unroll
    for (int i = 0; i < 4; ++i) {
      int m = m0 + rr + 16 * i;
      float4 f = *(const float4*)(x + (size_t)m * 3584 + kbase + k0 + cl);
      *(uint2*)(As + (size_t)(rr + 16 * i) * 72 + cl) = cvt4(f);
    }
#pragma unroll
    for (int i = 0; i < 4; ++i) {
      int n = r8 + 32 * i;
      *(bf16x8*)(Ws + (size_t)n * 72 + c8) =
          *(const bf16x8*)(Wb + (size_t)n * Kseg + k0 + c8);
    }
    __syncthreads();
#pragma unroll
    for (int ks = 0; ks < 2; ++ks) {
      bf16x8 af[4], bfr[2];
#pragma unroll
      for (int mf = 0; mf < 4; ++mf)
        af[mf] = *(const bf16x8*)(As + (size_t)(mf * 16 + ln) * 72 + ks * 32 + qd * 8);
#pragma unroll
      for (int nf = 0; nf < 2; ++nf)
        bfr[nf] = *(const bf16x8*)(Ws + (size_t)(w * 32 + nf * 16 + ln) * 72 + ks * 32 + qd * 8);
#pragma unroll
      for (int mf = 0; mf < 4; ++mf)
#pragma unroll
        for (int nf = 0; nf < 2; ++nf)
          acc[mf][nf] = __builtin_amdgcn_mfma_f32_16x16x32_bf16(af[mf], bfr[nf], acc[mf][nf], 0, 0, 0);
    }
  }

#pragma unroll
  for (int mf = 0; mf < 4; ++mf) {
#pragma unroll
    for (int r = 0; r < 4; ++r) {
      int m = m0 + mf * 16 + qd * 4 + r;
#pragma unroll
      for (int nf = 0; nf < 2; ++nf) {
        int n = w * 32 + nf * 16 + ln;
        float v = fmaxf(acc[mf][nf][r] + bias[n], 0.f);
        feats[(size_t)m * 512 + seg * 128 + n] = bf1(v);
      }
    }
  }
}

// ---------------------------------------------------------------------------
// becat GEMM: b0 = relu(cat(left,right) @ beW^T + b), A synthesized fp32
// from csum, W bf16, out bf16. 256 blocks.
// ---------------------------------------------------------------------------
__global__ __launch_bounds__(256) void gemm_becat64(
    const float* __restrict__ csum,
    const uint16_t* __restrict__ Wb, const float* __restrict__ bias,
    uint16_t* __restrict__ C)
{
  __shared__ __align__(16) uint16_t As[64 * 72];
  __shared__ __align__(16) uint16_t Ws[128 * 72];

  const int M = 16376, K = 256;
  const int t  = threadIdx.x;
  const int m0 = blockIdx.x * 64;
  const int w  = t >> 6, l = t & 63;
  const int ln = l & 15, qd = l >> 4;

  f32x4 acc[4][2];
#pragma unroll
  for (int i = 0; i < 4; ++i) { acc[i][0] = (f32x4){0,0,0,0}; acc[i][1] = (f32x4){0,0,0,0}; }

  const int rr = t >> 4;
  const int cl = (t & 15) * 4;
  const int r8 = t >> 3;
  const int c8 = (t & 7) * 8;

  for (int k0 = 0; k0 < K; k0 += 64) {
    __syncthreads();
#pragma unroll
    for (int i = 0; i < 4; ++i) {
      int m = m0 + rr + 16 * i;
      int mc = m < M ? m : M - 1;
      int j = mc >> 3, bb = mc & 7;
      int kk = k0 + cl;
      float4 f;
      if (kk < 128) {
        float4 v = *(const float4*)(csum + (size_t)mc * 128 + kk);
        float s = 1.f / (float)(j + 1);
        f = make_float4(v.x * s, v.y * s, v.z * s, v.w * s);
      } else {
        int d = kk - 128;
        float4 c0 = *(const float4*)(csum + (size_t)mc * 128 + d);
        float4 ct = *(const float4*)(csum + (size_t)(16376 + bb) * 128 + d);
        float s = 1.f / (float)(2047 - j);
        f = make_float4((ct.x - c0.x) * s, (ct.y - c0.y) * s,
                        (ct.z - c0.z) * s, (ct.w - c0.w) * s);
      }
      *(uint2*)(As + (size_t)(rr + 16 * i) * 72 + cl) = cvt4(f);
    }
#pragma unroll
    for (int i = 0; i < 4; ++i) {
      int n = r8 + 32 * i;
      *(bf16x8*)(Ws + (size_t)n * 72 + c8) =
          *(const bf16x8*)(Wb + (size_t)n * K + k0 + c8);
    }
    __syncthreads();
#pragma unroll
    for (int ks = 0; ks < 2; ++ks) {
      bf16x8 af[4], bfr[2];
#pragma unroll
      for (int mf = 0; mf < 4; ++mf)
        af[mf] = *(const bf16x8*)(As + (size_t)(mf * 16 + ln) * 72 + ks * 32 + qd * 8);
#pragma unroll
      for (int nf = 0; nf < 2; ++nf)
        bfr[nf] = *(const bf16x8*)(Ws + (size_t)(w * 32 + nf * 16 + ln) * 72 + ks * 32 + qd * 8);
#pragma unroll
      for (int mf = 0; mf < 4; ++mf)
#pragma unroll
        for (int nf = 0; nf < 2; ++nf)
          acc[mf][nf] = __builtin_amdgcn_mfma_f32_16x16x32_bf16(af[mf], bfr[nf], acc[mf][nf], 0, 0, 0);
    }
  }

#pragma unroll
  for (int mf = 0; mf < 4; ++mf) {
#pragma unroll
    for (int r = 0; r < 4; ++r) {
      int m = m0 + mf * 16 + qd * 4 + r;
      if (m < M) {
#pragma unroll
        for (int nf = 0; nf < 2; ++nf) {
          int n = w * 32 + nf * 16 + ln;
          C[(size_t)m * 128 + n] = bf1(fmaxf(acc[mf][nf][r] + bias[n], 0.f));
        }
      }
    }
  }
}

// ---------------------------------------------------------------------------
// vpack: V third of bf16 proj -> Vtb [b][tile32][d128][key64], keys permuted
// within tile: half position p = 4*(k&15) + (k>>4). grid (32,8), 256 thr.
// ---------------------------------------------------------------------------
__global__ __launch_bounds__(256) void vpack(
    const uint16_t* __restrict__ proj, uint16_t* __restrict__ Vtb, int Slen)
{
  __shared__ __align__(16) uint16_t Vs[64][136];

  const int kt = blockIdx.x, b = blockIdx.y, t = threadIdx.x;
  const int sl = t >> 2, cg = (t & 3) * 32;
  const int s  = kt * 64 + sl;
  const int valid = s < Slen;
  const int sc = valid ? s : Slen - 1;
  const uint16_t* src = proj + ((size_t)sc * 8 + b) * 384 + 256 + cg;
#pragma unroll
  for (int i = 0; i < 4; ++i) {
    bf16x8 v;
    if (valid) v = *(const bf16x8*)(src + i * 8);
    else       v = (bf16x8){0,0,0,0,0,0,0,0};
    *(bf16x8*)(&Vs[sl][cg + i * 8]) = v;
  }
  __syncthreads();
  const int d = t >> 1, hh = t & 1;
  uint32_t wv[16];
#pragma unroll
  for (int j = 0; j < 8; ++j) {
    int k0o = hh * 8 + j;
    wv[j * 2]     = (uint32_t)Vs[k0o][d]      | ((uint32_t)Vs[k0o + 16][d] << 16);
    wv[j * 2 + 1] = (uint32_t)Vs[k0o + 32][d] | ((uint32_t)Vs[k0o + 48][d] << 16);
  }
  uint16_t* dv = Vtb + (((size_t)b * 32 + kt) * 128 + d) * 64 + hh * 32;
#pragma unroll
  for (int i = 0; i < 4; ++i)
    *(uint4*)(dv + i * 8) = *(uint4*)(&wv[i * 4]);
}

// ---------------------------------------------------------------------------
// 3-way split-K flash attention over bf16 proj (Q,K direct) + packed Vt.
// splits: keys [704*z, min(Slen, 704*(z+1))) (z=2 takes the remainder).
// Stores UNNORMALIZED O partials + (m, l); combine3 merges.
// ---------------------------------------------------------------------------
__global__ __launch_bounds__(256, 3) void attn_split3(
    const uint16_t* __restrict__ proj, const uint16_t* __restrict__ Vtb,
    float* __restrict__ Opart, float* __restrict__ ml, int Slen)
{
  __shared__ __align__(16) uint16_t KsL[64 * 136];     // [key][k], pitch 136
  __shared__ __align__(16) uint16_t VtL[128 * 72];     // [d][k'],  pitch 72
  __shared__ __align__(16) uint16_t PbL[4][16 * 72];   // per-wave [q][k']

  const int t  = threadIdx.x;
  const int b  = blockIdx.y;
  const int q0 = blockIdx.x * 64;
  const int split = blockIdx.z;
  const int kbeg = split * 704;
  const int kend = (split == 2) ? Slen : kbeg + 704;
  const int w  = t >> 6;
  const int l  = t & 63;
  const int ln = l & 15;
  const int qd = l >> 4;
  const float scl = 0.08838834764831845f;   // 1/sqrt(128)

  bf16x8 qf[4];
  {
    int qrow = q0 + w * 16 + ln;
    int qc = qrow < Slen ? qrow : Slen - 1;
    const uint16_t* qp = proj + ((size_t)qc * 8 + b) * 384 + qd * 8;
#pragma unroll
    for (int ks = 0; ks < 4; ++ks) {
      union { bf16x8 v; uint16_t h[8]; uint32_t u[4]; } in, out;
      in.v = *(const bf16x8*)(qp + ks * 32);
#pragma unroll
      for (int j = 0; j < 4; ++j)
        out.u[j] = pk2bf(frombf(in.h[2 * j]) * scl, frombf(in.h[2 * j + 1]) * scl);
      qf[ks] = out.v;
    }
  }

  f32x4 oacc[8];
#pragma unroll
  for (int i = 0; i < 8; ++i) oacc[i] = (f32x4){0.f, 0.f, 0.f, 0.f};
  float mrow[4] = {-INFINITY, -INFINITY, -INFINITY, -INFINITY};
  float lrow[4] = {0.f, 0.f, 0.f, 0.f};

  const int ntiles = (kend - kbeg + 63) >> 6;
  for (int kt = 0; kt < ntiles; ++kt) {
    __syncthreads();
    { // stage K tile: 16B copies straight from bf16 proj
      const int key = t >> 2, cg = (t & 3) * 32;
      int kg = kbeg + kt * 64 + key;
      int kc = kg < Slen ? kg : Slen - 1;
      const uint16_t* src = proj + ((size_t)kc * 8 + b) * 384 + 128 + cg;
      uint16_t* dst = KsL + key * 136 + cg;
#pragma unroll
      for (int i = 0; i < 4; ++i)
        *(bf16x8*)(dst + i * 8) = *(const bf16x8*)(src + i * 8);
    }
    { // stage Vt tile from packed buffer (transposed+permuted already)
      const int d = t >> 1, h2 = (t & 1) * 32;
      const int tile = 11 * split + kt;
      const uint16_t* src = Vtb + (((size_t)b * 32 + tile) * 128 + d) * 64 + h2;
      uint16_t* dst = VtL + d * 72 + h2;
#pragma unroll
      for (int i = 0; i < 4; ++i)
        *(bf16x8*)(dst + i * 8) = *(const bf16x8*)(src + i * 8);
    }
    __syncthreads();

    f32x4 sc[4];
#pragma unroll
    for (int nf = 0; nf < 4; ++nf) {
      f32x4 acc = (f32x4){0.f, 0.f, 0.f, 0.f};
#pragma unroll
      for (int ks = 0; ks < 4; ++ks) {
        bf16x8 kf = *(const bf16x8*)(KsL + (size_t)(nf * 16 + ln) * 136 + ks * 32 + qd * 8);
        acc = __builtin_amdgcn_mfma_f32_16x16x32_bf16(qf[ks], kf, acc, 0, 0, 0);
      }
      int key = kbeg + kt * 64 + nf * 16 + ln;
      if (key >= kend) { acc[0] = -1e30f; acc[1] = -1e30f; acc[2] = -1e30f; acc[3] = -1e30f; }
      sc[nf] = acc;
    }

    float alphaR[4];
#pragma unroll
    for (int r = 0; r < 4; ++r) {
      float mx = fmaxf(fmaxf(sc[0][r], sc[1][r]), fmaxf(sc[2][r], sc[3][r]));
      mx = fmaxf(mx, __shfl_xor(mx, 1));
      mx = fmaxf(mx, __shfl_xor(mx, 2));
      mx = fmaxf(mx, __shfl_xor(mx, 4));
      mx = fmaxf(mx, __shfl_xor(mx, 8));
      float mNew = fmaxf(mrow[r], mx);
      float p0 = __expf(sc[0][r] - mNew);
      float p1 = __expf(sc[1][r] - mNew);
      float p2 = __expf(sc[2][r] - mNew);
      float p3 = __expf(sc[3][r] - mNew);
      float ps = p0 + p1 + p2 + p3;
      ps += __shfl_xor(ps, 1);
      ps += __shfl_xor(ps, 2);
      ps += __shfl_xor(ps, 4);
      ps += __shfl_xor(ps, 8);
      float alpha = __expf(mrow[r] - mNew);
      mrow[r] = mNew;
      lrow[r] = lrow[r] * alpha + ps;
      alphaR[r] = alpha;
      uint2 pk;
      pk.x = pk2bf(p0, p1);
      pk.y = pk2bf(p2, p3);
      *(uint2*)(PbL[w] + (size_t)(qd * 4 + r) * 72 + ln * 4) = pk;
    }
#pragma unroll
    for (int no = 0; no < 8; ++no) {
#pragma unroll
      for (int r = 0; r < 4; ++r) oacc[no][r] *= alphaR[r];
    }
    __asm__ volatile("s_waitcnt lgkmcnt(0)" ::: "memory");

#pragma unroll
    for (int ks2 = 0; ks2 < 2; ++ks2) {
      bf16x8 af = *(const bf16x8*)(PbL[w] + (size_t)ln * 72 + ks2 * 32 + qd * 8);
#pragma unroll
      for (int no = 0; no < 8; ++no) {
        bf16x8 vf = *(const bf16x8*)(VtL + (size_t)(no * 16 + ln) * 72 + ks2 * 32 + qd * 8);
        oacc[no] = __builtin_amdgcn_mfma_f32_16x16x32_bf16(af, vf, oacc[no], 0, 0, 0);
      }
    }
  }

#pragma unroll
  for (int r = 0; r < 4; ++r) {
    int qg = q0 + w * 16 + qd * 4 + r;
    if (qg < Slen) {
      size_t row = (size_t)qg * 8 + b;
      float* dst = Opart + ((size_t)split * 16384 + row) * 128 + ln;
#pragma unroll
      for (int no = 0; no < 8; ++no) dst[no * 16] = oacc[no][r];
      if (ln == 0) {
        ml[((size_t)split * 16384 + row) * 2 + 0] = mrow[r];
        ml[((size_t)split * 16384 + row) * 2 + 1] = lrow[r];
      }
    }
  }
}

// Exact merge of 3 split partials -> bf16 attention output.
__global__ __launch_bounds__(256) void attn_combine3(
    const float* __restrict__ Opart, const float* __restrict__ ml,
    uint16_t* __restrict__ out, int rows)
{
  int idx = blockIdx.x * 256 + threadIdx.x;   // one per (row, 4-elem group)
  int row = idx >> 5;
  int d   = (idx & 31) * 4;
  if (row >= rows) return;
  float m0 = ml[(size_t)row * 2],                 l0 = ml[(size_t)row * 2 + 1];
  float m1 = ml[((size_t)16384 + row) * 2],       l1 = ml[((size_t)16384 + row) * 2 + 1];
  float m2 = ml[((size_t)32768 + row) * 2],       l2 = ml[((size_t)32768 + row) * 2 + 1];
  float M = fmaxf(fmaxf(m0, m1), m2);
  float w0 = __expf(m0 - M), w1 = __expf(m1 - M), w2 = __expf(m2 - M);
  float inv = 1.f / (l0 * w0 + l1 * w1 + l2 * w2);
  float4 a = *(const float4*)(Opart + (size_t)row * 128 + d);
  float4 c = *(const float4*)(Opart + ((size_t)16384 + row) * 128 + d);
  float4 e = *(const float4*)(Opart + ((size_t)32768 + row) * 128 + d);
  float4 o = make_float4((a.x * w0 + c.x * w1 + e.x * w2) * inv,
                         (a.y * w0 + c.y * w1 + e.y * w2) * inv,
                         (a.z * w0 + c.z * w1 + e.z * w2) * inv,
                         (a.w * w0 + c.w * w1 + e.w * w2) * inv);
  *(uint2*)(out + (size_t)row * 128 + d) = cvt4(o);
}

// ---------------------------------------------------------------------------
// Cumsum over s of e (S,B,128), 32 chunks x 64 rows (256 blocks).
// ---------------------------------------------------------------------------
__global__ void cumsum_p1(const float* __restrict__ e, float* __restrict__ csum,
                          float* __restrict__ part)
{
  int chunk = blockIdx.x, b = blockIdx.y, d = threadIdx.x;
  float run = 0.f;
  int s0 = chunk * 64;
  for (int s = 0; s < 64; ++s) {
    size_t idx = ((size_t)(s0 + s) * 8 + b) * 128 + d;
    run += e[idx];
    csum[idx] = run;
  }
  part[(b * 32 + chunk) * 128 + d] = run;
}

__global__ void cumsum_p2(float* __restrict__ part)
{
  int b = blockIdx.x, d = threadIdx.x;
  float run = 0.f;
  for (int c = 0; c < 32; ++c) {
    float v = part[(b * 32 + c) * 128 + d];
    part[(b * 32 + c) * 128 + d] = run;
    run += v;
  }
}

__global__ void cumsum_p3(float* __restrict__ csum, const float* __restrict__ part)
{
  int chunk = blockIdx.x, b = blockIdx.y, d = threadIdx.x;
  float off = part[(b * 32 + chunk) * 128 + d];
  int s0 = chunk * 64;
  for (int s = 0; s < 64; ++s)
    csum[((size_t)(s0 + s) * 8 + b) * 128 + d] += off;
}

// ---------------------------------------------------------------------------
// bout GEMM (A bf16, K=128) with fused bpW-dot + sigmoid head epilogue.
// ---------------------------------------------------------------------------
__global__ __launch_bounds__(256) void gemm_bout_head(
    const uint16_t* __restrict__ A,
    const uint16_t* __restrict__ Wb,
    const float* __restrict__ bias,
    const float* __restrict__ bpW, const float* __restrict__ bpb,
    float* __restrict__ out, int M)
{
  __shared__ __align__(16) uint16_t As[64 * 72];
  __shared__ __align__(16) uint16_t Ws[128 * 72];
  __shared__ float Ct[64][133];

  const int K = 128;
  const int t  = threadIdx.x;
  const int m0 = blockIdx.x * 64;
  const int w  = t >> 6, l = t & 63;
  const int ln = l & 15, qd = l >> 4;

  f32x4 acc[4][2];
#pragma unroll
  for (int i = 0; i < 4; ++i) { acc[i][0] = (f32x4){0,0,0,0}; acc[i][1] = (f32x4){0,0,0,0}; }

  const int r8 = t >> 3;
  const int c8 = (t & 7) * 8;

  for (int k0 = 0; k0 < K; k0 += 64) {
    __syncthreads();
#pragma unroll
    for (int i = 0; i < 2; ++i) {
      int m = m0 + r8 + 32 * i;
      int mc = m < M ? m : M - 1;
      *(bf16x8*)(As + (size_t)(r8 + 32 * i) * 72 + c8) =
          *(const bf16x8*)(A + (size_t)mc * 128 + k0 + c8);
    }
#pragma unroll
    for (int i = 0; i < 4; ++i) {
      int n = r8 + 32 * i;
      *(bf16x8*)(Ws + (size_t)n * 72 + c8) =
          *(const bf16x8*)(Wb + (size_t)n * K + k0 + c8);
    }
    __syncthreads();
#pragma unroll
    for (int ks = 0; ks < 2; ++ks) {
      bf16x8 af[4], bfr[2];
#pragma unroll
      for (int mf = 0; mf < 4; ++mf)
        af[mf] = *(const bf16x8*)(As + (size_t)(mf * 16 + ln) * 72 + ks * 32 + qd * 8);
#pragma unroll
      for (int nf = 0; nf < 2; ++nf)
        bfr[nf] = *(const bf16x8*)(Ws + (size_t)(w * 32 + nf * 16 + ln) * 72 + ks * 32 + qd * 8);
#pragma unroll
      for (int mf = 0; mf < 4; ++mf)
#pragma unroll
        for (int nf = 0; nf < 2; ++nf)
          acc[mf][nf] = __builtin_amdgcn_mfma_f32_16x16x32_bf16(af[mf], bfr[nf], acc[mf][nf], 0, 0, 0);
    }
  }

  __syncthreads();
#pragma unroll
  for (int mf = 0; mf < 4; ++mf) {
#pragma unroll
    for (int r = 0; r < 4; ++r) {
      int rowL = mf * 16 + qd * 4 + r;
#pragma unroll
      for (int nf = 0; nf < 2; ++nf) {
        int n = w * 32 + nf * 16 + ln;
        Ct[rowL][n] = acc[mf][nf][r] + bias[n];
      }
    }
  }
  __syncthreads();
  {
    int row = t >> 2, qg = t & 3;
    int m = m0 + row;
    float p = 0.f;
#pragma unroll
    for (int j = 0; j < 32; ++j) {
      int c = qg + j * 4;
      p += Ct[row][c] * bpW[c];
    }
    p += __shfl_xor(p, 1);
    p += __shfl_xor(p, 2);
    if (qg == 0 && m < M)
      out[m] = 1.f / (1.f + __expf(-(p + bpb[0])));
  }
}

// ---------------------------------------------------------------------------
extern "C" void kernel_launch(void* const* d_in, const int* in_sizes, int n_in,
                              void* d_out, int out_size, void* d_ws, size_t ws_size,
                              hipStream_t stream)
{
  const float* x       = (const float*)d_in[0];
  const float* pW      = (const float*)d_in[1];
  const float* pb      = (const float*)d_in[2];
  const float* cW      = (const float*)d_in[3];
  const float* cb      = (const float*)d_in[4];
  const float* aW      = (const float*)d_in[5];
  const float* ab      = (const float*)d_in[6];
  const float* uW      = (const float*)d_in[7];
  const float* ub      = (const float*)d_in[8];
  const float* eW      = (const float*)d_in[9];
  const float* eb      = (const float*)d_in[10];
  const float* la_win  = (const float*)d_in[11];
  const float* la_bin  = (const float*)d_in[12];
  const float* la_wout = (const float*)d_in[13];
  const float* la_bout = (const float*)d_in[14];
  const float* beW     = (const float*)d_in[15];
  const float* beb     = (const float*)d_in[16];
  const float* ba_win  = (const float*)d_in[17];
  const float* ba_bin  = (const float*)d_in[18];
  const float* ba_wout = (const float*)d_in[19];
  const float* ba_bout = (const float*)d_in[20];
  const float* bpW     = (const float*)d_in[21];
  const float* bpb     = (const float*)d_in[22];

  float* ws   = (float*)d_ws;
  float* outF = (float*)d_out;

  // Workspace plan (float offsets):
  //  [0, 344064)                WB: bf16 weights (688128 halves)
  //  M0=344064:
  //  [M0, +4,194,304)           feats bf16 (dead after e0) / csum fp32 (2,097,152)
  //  [M0+2,097,152, +32,768)    partB (coexists only with csum)
  //  [M0+4,194,304, +1,048,576) e0 / att1 / b0 / att2 bf16 (serial)
  //  [M0+5,242,880, +3,145,728) proj bf16 (alive through attention)
  //  [M0+8,388,608, +1,048,576) Vtb bf16
  //  [M0+9,437,184, +6,291,456) Opart fp32 (3 splits)
  //  [M0+15,728,640, +98,304)   ml (3 splits)
  uint16_t* WB  = (uint16_t*)ws;
  float* base   = ws + 344064;
  uint16_t* featsB = (uint16_t*)base;
  float* csumB  = base;
  float* partB  = base + 2097152;
  uint16_t* eB  = (uint16_t*)(base + 4194304);   // e0/att1/b0/att2
  uint16_t* projB = (uint16_t*)(base + 5242880);
  uint16_t* VtbB  = (uint16_t*)(base + 8388608);
  float* OpartB = base + 9437184;
  float* mlB    = base + 15728640;

  // 0. weights -> bf16
  WPtrs wp;
  wp.p[0] = pW; wp.p[1] = cW; wp.p[2] = aW; wp.p[3] = uW; wp.p[4] = eW;
  wp.p[5] = la_win; wp.p[6] = la_wout; wp.p[7] = beW; wp.p[8] = ba_win; wp.p[9] = ba_wout;
  pack_weights<<<dim3(672), 256, 0, stream>>>(wp, WB);

  // 1. feats = relu(segment linears) -> bf16
  gemm_feats64<<<dim3(256, 4), 256, 0, stream>>>(x, WB, pb, cb, ab, ub, featsB);
  // 2. e0 = relu(feats @ eW^T + eb) -> bf16, remapped (B,S)->(S,B)
  gemm64<true, true, true, true><<<dim3(256, 1), 256, 0, stream>>>(
      featsB, 512, WB + OFF_EW, eb, eB, 128, 16384, 512);
  // 3. proj1 = e0 @ la_win^T + la_bin -> bf16
  gemm64<true, true, false, false><<<dim3(256, 3), 256, 0, stream>>>(
      eB, 128, WB + OFF_LAWIN, la_bin, projB, 384, 16384, 128);
  // 4. V pack + 3-split flash + combine (att1 -> bf16 in eB)
  vpack<<<dim3(32, 8), 256, 0, stream>>>(projB, VtbB, 2048);
  attn_split3<<<dim3(32, 8, 3), 256, 0, stream>>>(projB, VtbB, OpartB, mlB, 2048);
  attn_combine3<<<dim3(2048), 256, 0, stream>>>(OpartB, mlB, eB, 16384);
  // 5. e = att1 @ la_wout^T + la_bout -> d_out (fp32)
  gemm64<true, false, false, false><<<dim3(256, 1), 256, 0, stream>>>(
      eB, 128, WB + OFF_LAWOUT, la_bout, outF, 128, 16384, 128);
  // 6-8. csum
  cumsum_p1<<<dim3(32, 8), 128, 0, stream>>>(outF, csumB, partB);
  cumsum_p2<<<dim3(8), 128, 0, stream>>>(partB);
  cumsum_p3<<<dim3(32, 8), 128, 0, stream>>>(csumB, partB);
  // 9. b0 = relu(cat(left,right) @ beW^T + beb) -> bf16
  gemm_becat64<<<dim3(256), 256, 0, stream>>>(csumB, WB + OFF_BEW, beb, eB);
  // 10. proj2
  gemm64<true, true, false, false><<<dim3(256, 3), 256, 0, stream>>>(
      eB, 128, WB + OFF_BAWIN, ba_bin, projB, 384, 16376, 128);
  // 11. V pack + att2 (Slen=2047) + combine (att2 -> bf16 in eB)
  vpack<<<dim3(32, 8), 256, 0, stream>>>(projB, VtbB, 2047);
  attn_split3<<<dim3(32, 8, 3), 256, 0, stream>>>(projB, VtbB, OpartB, mlB, 2047);
  attn_combine3<<<dim3(2047), 256, 0, stream>>>(OpartB, mlB, eB, 16376);
  // 12+13. bout GEMM with fused sigmoid head -> d_out tail
  gemm_bout_head<<<dim3(256), 256, 0, stream>>>(
      eB, WB + OFF_BAWOUT, ba_bout, bpW, bpb, outF + 2097152, 16376);
}

// Round 4
// 537.219 us; speedup vs baseline: 1.2576x; 1.0302x over previous
//
#include <hip/hip_runtime.h>
#include <hip/hip_bf16.h>
#include <math.h>
#include <stdint.h>

// ---------------------------------------------------------------------------
// SceneSegmenter Round 8: latency-hiding + fusion round.
//  - attn_split3: T14 async-stage (prefetch next K/V tile into regs during
//    compute; LDS write at loop top) — hides global latency under MFMA.
//  - gemm_attc64<HEAD>: out-proj GEMMs read Opart+ml directly (split combine
//    inlined into A-staging, identical arithmetic) — kills combine kernels.
//  - gemm_becat64: cumsum chunk-offset (p3) fused into A synthesis.
//  - cumsum: 64 chunks x 32 rows (512 blocks p1).
// Layouts: token-major activations (S, B, D) flat, row = s*8+b.
// ---------------------------------------------------------------------------

#define DEV static __device__ __forceinline__

typedef __attribute__((ext_vector_type(8))) short bf16x8;   // 8 bf16 (4 VGPRs)
typedef __attribute__((ext_vector_type(4))) float f32x4;    // MFMA C/D

DEV uint32_t pk2bf(float a, float b) {       // packed fp32x2 -> bf16x2 (RNE)
  __hip_bfloat162 h = __float22bfloat162_rn(make_float2(a, b));
  return *(uint32_t*)&h;
}
DEV uint2 cvt4(float4 f) {                   // 4 fp32 -> 4 bf16
  return make_uint2(pk2bf(f.x, f.y), pk2bf(f.z, f.w));
}
DEV uint16_t bf1(float a) { return (uint16_t)(pk2bf(a, 0.f) & 0xffffu); }
DEV float frombf(uint16_t h) {
  union { uint32_t u; float f; } v; v.u = ((uint32_t)h) << 16; return v.f;
}

// Weight-pack offsets (halves) inside WB
#define OFF_PW      0u
#define OFF_CW      262144u
#define OFF_AW      327680u
#define OFF_UW      393216u
#define OFF_EW      458752u
#define OFF_LAWIN   524288u
#define OFF_LAWOUT  573440u
#define OFF_BEW     589824u
#define OFF_BAWIN   622592u
#define OFF_BAWOUT  671744u
#define OFF_END     688128u

struct WPtrs { const float* p[10]; };

// ---------------------------------------------------------------------------
// pack_weights: concatenated fp32 weights -> bf16 WB. 672 blocks x 256 thr.
// ---------------------------------------------------------------------------
__global__ __launch_bounds__(256) void pack_weights(WPtrs wp, uint16_t* __restrict__ WB)
{
  const uint32_t off[11] = {OFF_PW, OFF_CW, OFF_AW, OFF_UW, OFF_EW, OFF_LAWIN,
                            OFF_LAWOUT, OFF_BEW, OFF_BAWIN, OFF_BAWOUT, OFF_END};
  uint32_t h = (blockIdx.x * 256u + threadIdx.x) * 4u;
  if (h >= OFF_END) return;
  int s = 0;
  while (h >= off[s + 1]) ++s;
  float4 f = *(const float4*)(wp.p[s] + (h - off[s]));
  *(uint2*)(WB + h) = cvt4(f);
}

// ---------------------------------------------------------------------------
// Templated bf16 MFMA GEMM, BM=64 x BN=128, BK=64, 256 thr = 4 waves.
// W always pre-packed bf16. A either bf16 (pure copy) or fp32 (cvt).
// ---------------------------------------------------------------------------
template<bool ABF, bool OBF, bool RELU, bool REMAP>
__global__ __launch_bounds__(256) void gemm64(
    const void* __restrict__ Ap, int lda,
    const uint16_t* __restrict__ Wb,
    const float* __restrict__ bias,
    void* __restrict__ Cp, int ldc,
    int M, int K)
{
  __shared__ __align__(16) uint16_t As[64 * 72];
  __shared__ __align__(16) uint16_t Ws[128 * 72];

  const int t  = threadIdx.x;
  const int m0 = blockIdx.x * 64;
  const int n0 = blockIdx.y * 128;
  const int w  = t >> 6, l = t & 63;
  const int ln = l & 15, qd = l >> 4;

  f32x4 acc[4][2];
#pragma unroll
  for (int i = 0; i < 4; ++i) { acc[i][0] = (f32x4){0,0,0,0}; acc[i][1] = (f32x4){0,0,0,0}; }

  const int rr = t >> 4;          // fp32-A path: 16 rows
  const int cl = (t & 15) * 4;
  const int r8 = t >> 3;          // bf16 paths: 32 rows
  const int c8 = (t & 7) * 8;     // half col (16B)

  for (int k0 = 0; k0 < K; k0 += 64) {
    __syncthreads();
    if (ABF) {
      const uint16_t* A = (const uint16_t*)Ap;
#pragma unroll
      for (int i = 0; i < 2; ++i) {
        int m = m0 + r8 + 32 * i;
        int mc = m < M ? m : M - 1;
        *(bf16x8*)(As + (size_t)(r8 + 32 * i) * 72 + c8) =
            *(const bf16x8*)(A + (size_t)mc * lda + k0 + c8);
      }
    } else {
      const float* A = (const float*)Ap;
#pragma unroll
      for (int i = 0; i < 4; ++i) {
        int m = m0 + rr + 16 * i;
        int mc = m < M ? m : M - 1;
        float4 f = *(const float4*)(A + (size_t)mc * lda + k0 + cl);
        *(uint2*)(As + (size_t)(rr + 16 * i) * 72 + cl) = cvt4(f);
      }
    }
#pragma unroll
    for (int i = 0; i < 4; ++i) {           // W tile: 128 rows, pure copy
      int n = r8 + 32 * i;
      *(bf16x8*)(Ws + (size_t)n * 72 + c8) =
          *(const bf16x8*)(Wb + (size_t)(n0 + n) * K + k0 + c8);
    }
    __syncthreads();
#pragma unroll
    for (int ks = 0; ks < 2; ++ks) {
      bf16x8 af[4], bfr[2];
#pragma unroll
      for (int mf = 0; mf < 4; ++mf)
        af[mf] = *(const bf16x8*)(As + (size_t)(mf * 16 + ln) * 72 + ks * 32 + qd * 8);
#pragma unroll
      for (int nf = 0; nf < 2; ++nf)
        bfr[nf] = *(const bf16x8*)(Ws + (size_t)(w * 32 + nf * 16 + ln) * 72 + ks * 32 + qd * 8);
#pragma unroll
      for (int mf = 0; mf < 4; ++mf)
#pragma unroll
        for (int nf = 0; nf < 2; ++nf)
          acc[mf][nf] = __builtin_amdgcn_mfma_f32_16x16x32_bf16(af[mf], bfr[nf], acc[mf][nf], 0, 0, 0);
    }
  }

#pragma unroll
  for (int mf = 0; mf < 4; ++mf) {
#pragma unroll
    for (int r = 0; r < 4; ++r) {
      int m = m0 + mf * 16 + qd * 4 + r;
      if (m < M) {
        size_t ro = REMAP ? (size_t)((m & 2047) * 8 + (m >> 11)) : (size_t)m;
#pragma unroll
        for (int nf = 0; nf < 2; ++nf) {
          int n = n0 + w * 32 + nf * 16 + ln;
          float v = acc[mf][nf][r] + bias[n];
          if (RELU) v = fmaxf(v, 0.f);
          if (OBF) ((uint16_t*)Cp)[ro * (size_t)ldc + n] = bf1(v);
          else     ((float*)Cp)[ro * (size_t)ldc + n] = v;
        }
      }
    }
  }
}

// ---------------------------------------------------------------------------
// Fused 4-segment feats GEMM (A = x fp32, W bf16 pre-packed, out bf16).
// ---------------------------------------------------------------------------
__global__ __launch_bounds__(256) void gemm_feats64(
    const float* __restrict__ x, const uint16_t* __restrict__ WB,
    const float* __restrict__ pb, const float* __restrict__ cb,
    const float* __restrict__ ab, const float* __restrict__ ub,
    uint16_t* __restrict__ feats)
{
  __shared__ __align__(16) uint16_t As[64 * 72];
  __shared__ __align__(16) uint16_t Ws[128 * 72];

  const int seg = blockIdx.y;
  const uint16_t* Wb; const float* bias; int kbase, Kseg;
  if (seg == 0)      { Wb = WB + OFF_PW; bias = pb; kbase = 0;    Kseg = 2048; }
  else if (seg == 1) { Wb = WB + OFF_CW; bias = cb; kbase = 2048; Kseg = 512; }
  else if (seg == 2) { Wb = WB + OFF_AW; bias = ab; kbase = 2560; Kseg = 512; }
  else               { Wb = WB + OFF_UW; bias = ub; kbase = 3072; Kseg = 512; }

  const int t  = threadIdx.x;
  const int m0 = blockIdx.x * 64;
  const int w  = t >> 6, l = t & 63;
  const int ln = l & 15, qd = l >> 4;

  f32x4 acc[4][2];
#pragma unroll
  for (int i = 0; i < 4; ++i) { acc[i][0] = (f32x4){0,0,0,0}; acc[i][1] = (f32x4){0,0,0,0}; }

  const int rr = t >> 4;
  const int cl = (t & 15) * 4;
  const int r8 = t >> 3;
  const int c8 = (t & 7) * 8;

  for (int k0 = 0; k0 < Kseg; k0 += 64) {
    __syncthreads();
#pragma unroll
    for (int i = 0; i < 4; ++i) {
      int m = m0 + rr + 16 * i;
      float4 f = *(const float4*)(x + (size_t)m * 3584 + kbase + k0 + cl);
      *(uint2*)(As + (size_t)(rr + 16 * i) * 72 + cl) = cvt4(f);
    }
#pragma unroll
    for (int i = 0; i < 4; ++i) {
      int n = r8 + 32 * i;
      *(bf16x8*)(Ws + (size_t)n * 72 + c8) =
          *(const bf16x8*)(Wb + (size_t)n * Kseg + k0 + c8);
    }
    __syncthreads();
#pragma unroll
    for (int ks = 0; ks < 2; ++ks) {
      bf16x8 af[4], bfr[2];
#pragma unroll
      for (int mf = 0; mf < 4; ++mf)
        af[mf] = *(const bf16x8*)(As + (size_t)(mf * 16 + ln) * 72 + ks * 32 + qd * 8);
#pragma unroll
      for (int nf = 0; nf < 2; ++nf)
        bfr[nf] = *(const bf16x8*)(Ws + (size_t)(w * 32 + nf * 16 + ln) * 72 + ks * 32 + qd * 8);
#pragma unroll
      for (int mf = 0; mf < 4; ++mf)
#pragma unroll
        for (int nf = 0; nf < 2; ++nf)
          acc[mf][nf] = __builtin_amdgcn_mfma_f32_16x16x32_bf16(af[mf], bfr[nf], acc[mf][nf], 0, 0, 0);
    }
  }

#pragma unroll
  for (int mf = 0; mf < 4; ++mf) {
#pragma unroll
    for (int r = 0; r < 4; ++r) {
      int m = m0 + mf * 16 + qd * 4 + r;
#pragma unroll
      for (int nf = 0; nf < 2; ++nf) {
        int n = w * 32 + nf * 16 + ln;
        float v = fmaxf(acc[mf][nf][r] + bias[n], 0.f);
        feats[(size_t)m * 512 + seg * 128 + n] = bf1(v);
      }
    }
  }
}

// ---------------------------------------------------------------------------
// becat GEMM with fused cumsum chunk-offset (p3): b0 = relu(cat @ beW^T + b).
// csum holds per-chunk local prefixes (32 rows/chunk); part[b*64+chunk] holds
// exclusive chunk offsets (after p2). Identical arithmetic to p3-then-read.
// ---------------------------------------------------------------------------
__global__ __launch_bounds__(256) void gemm_becat64(
    const float* __restrict__ csum, const float* __restrict__ part,
    const uint16_t* __restrict__ Wb, const float* __restrict__ bias,
    uint16_t* __restrict__ C)
{
  __shared__ __align__(16) uint16_t As[64 * 72];
  __shared__ __align__(16) uint16_t Ws[128 * 72];

  const int M = 16376, K = 256;
  const int t  = threadIdx.x;
  const int m0 = blockIdx.x * 64;
  const int w  = t >> 6, l = t & 63;
  const int ln = l & 15, qd = l >> 4;

  f32x4 acc[4][2];
#pragma unroll
  for (int i = 0; i < 4; ++i) { acc[i][0] = (f32x4){0,0,0,0}; acc[i][1] = (f32x4){0,0,0,0}; }

  const int rr = t >> 4;
  const int cl = (t & 15) * 4;
  const int r8 = t >> 3;
  const int c8 = (t & 7) * 8;

  for (int k0 = 0; k0 < K; k0 += 64) {
    __syncthreads();
#pragma unroll
    for (int i = 0; i < 4; ++i) {
      int m = m0 + rr + 16 * i;
      int mc = m < M ? m : M - 1;
      int j = mc >> 3, bb = mc & 7;
      int kk = k0 + cl;
      float4 f;
      if (kk < 128) {
        float4 v = *(const float4*)(csum + (size_t)mc * 128 + kk);
        float4 p = *(const float4*)(part + (size_t)(bb * 64 + (j >> 5)) * 128 + kk);
        float s = 1.f / (float)(j + 1);
        f = make_float4((v.x + p.x) * s, (v.y + p.y) * s,
                        (v.z + p.z) * s, (v.w + p.w) * s);
      } else {
        int d = kk - 128;
        float4 c0 = *(const float4*)(csum + (size_t)mc * 128 + d);
        float4 p0 = *(const float4*)(part + (size_t)(bb * 64 + (j >> 5)) * 128 + d);
        float4 ct = *(const float4*)(csum + (size_t)(16376 + bb) * 128 + d);
        float4 pt = *(const float4*)(part + (size_t)(bb * 64 + 63) * 128 + d);
        float s = 1.f / (float)(2047 - j);
        f = make_float4(((ct.x + pt.x) - (c0.x + p0.x)) * s,
                        ((ct.y + pt.y) - (c0.y + p0.y)) * s,
                        ((ct.z + pt.z) - (c0.z + p0.z)) * s,
                        ((ct.w + pt.w) - (c0.w + p0.w)) * s);
      }
      *(uint2*)(As + (size_t)(rr + 16 * i) * 72 + cl) = cvt4(f);
    }
#pragma unroll
    for (int i = 0; i < 4; ++i) {
      int n = r8 + 32 * i;
      *(bf16x8*)(Ws + (size_t)n * 72 + c8) =
          *(const bf16x8*)(Wb + (size_t)n * K + k0 + c8);
    }
    __syncthreads();
#pragma unroll
    for (int ks = 0; ks < 2; ++ks) {
      bf16x8 af[4], bfr[2];
#pragma unroll
      for (int mf = 0; mf < 4; ++mf)
        af[mf] = *(const bf16x8*)(As + (size_t)(mf * 16 + ln) * 72 + ks * 32 + qd * 8);
#pragma unroll
      for (int nf = 0; nf < 2; ++nf)
        bfr[nf] = *(const bf16x8*)(Ws + (size_t)(w * 32 + nf * 16 + ln) * 72 + ks * 32 + qd * 8);
#pragma unroll
      for (int mf = 0; mf < 4; ++mf)
#pragma unroll
        for (int nf = 0; nf < 2; ++nf)
          acc[mf][nf] = __builtin_amdgcn_mfma_f32_16x16x32_bf16(af[mf], bfr[nf], acc[mf][nf], 0, 0, 0);
    }
  }

#pragma unroll
  for (int mf = 0; mf < 4; ++mf) {
#pragma unroll
    for (int r = 0; r < 4; ++r) {
      int m = m0 + mf * 16 + qd * 4 + r;
      if (m < M) {
#pragma unroll
        for (int nf = 0; nf < 2; ++nf) {
          int n = w * 32 + nf * 16 + ln;
          C[(size_t)m * 128 + n] = bf1(fmaxf(acc[mf][nf][r] + bias[n], 0.f));
        }
      }
    }
  }
}

// ---------------------------------------------------------------------------
// vpack: V third of bf16 proj -> Vtb [b][tile32][d128][key64], keys permuted.
// ---------------------------------------------------------------------------
__global__ __launch_bounds__(256) void vpack(
    const uint16_t* __restrict__ proj, uint16_t* __restrict__ Vtb, int Slen)
{
  __shared__ __align__(16) uint16_t Vs[64][136];

  const int kt = blockIdx.x, b = blockIdx.y, t = threadIdx.x;
  const int sl = t >> 2, cg = (t & 3) * 32;
  const int s  = kt * 64 + sl;
  const int valid = s < Slen;
  const int sc = valid ? s : Slen - 1;
  const uint16_t* src = proj + ((size_t)sc * 8 + b) * 384 + 256 + cg;
#pragma unroll
  for (int i = 0; i < 4; ++i) {
    bf16x8 v;
    if (valid) v = *(const bf16x8*)(src + i * 8);
    else       v = (bf16x8){0,0,0,0,0,0,0,0};
    *(bf16x8*)(&Vs[sl][cg + i * 8]) = v;
  }
  __syncthreads();
  const int d = t >> 1, hh = t & 1;
  uint32_t wv[16];
#pragma unroll
  for (int j = 0; j < 8; ++j) {
    int k0o = hh * 8 + j;
    wv[j * 2]     = (uint32_t)Vs[k0o][d]      | ((uint32_t)Vs[k0o + 16][d] << 16);
    wv[j * 2 + 1] = (uint32_t)Vs[k0o + 32][d] | ((uint32_t)Vs[k0o + 48][d] << 16);
  }
  uint16_t* dv = Vtb + (((size_t)b * 32 + kt) * 128 + d) * 64 + hh * 32;
#pragma unroll
  for (int i = 0; i < 4; ++i)
    *(uint4*)(dv + i * 8) = *(uint4*)(&wv[i * 4]);
}

// ---------------------------------------------------------------------------
// 3-way split-K flash attention, T14 async-stage: prefetch next tile into
// regs during compute; LDS write at loop top. Q,K direct from bf16 proj.
// ---------------------------------------------------------------------------
__global__ __launch_bounds__(256, 3) void attn_split3(
    const uint16_t* __restrict__ proj, const uint16_t* __restrict__ Vtb,
    float* __restrict__ Opart, float* __restrict__ ml, int Slen)
{
  __shared__ __align__(16) uint16_t KsL[64 * 136];     // [key][k], pitch 136
  __shared__ __align__(16) uint16_t VtL[128 * 72];     // [d][k'],  pitch 72
  __shared__ __align__(16) uint16_t PbL[4][16 * 72];   // per-wave [q][k']

  const int t  = threadIdx.x;
  const int b  = blockIdx.y;
  const int q0 = blockIdx.x * 64;
  const int split = blockIdx.z;
  const int kbeg = split * 704;
  const int kend = (split == 2) ? Slen : kbeg + 704;
  const int w  = t >> 6;
  const int l  = t & 63;
  const int ln = l & 15;
  const int qd = l >> 4;
  const float scl = 0.08838834764831845f;   // 1/sqrt(128)

  const int kkey = t >> 2, kcg = (t & 3) * 32;   // K staging map
  const int vd   = t >> 1, vh  = (t & 1) * 32;   // V staging map

  bf16x8 qf[4];
  {
    int qrow = q0 + w * 16 + ln;
    int qc = qrow < Slen ? qrow : Slen - 1;
    const uint16_t* qp = proj + ((size_t)qc * 8 + b) * 384 + qd * 8;
#pragma unroll
    for (int ks = 0; ks < 4; ++ks) {
      union { bf16x8 v; uint16_t h[8]; uint32_t u[4]; } in, out;
      in.v = *(const bf16x8*)(qp + ks * 32);
#pragma unroll
      for (int j = 0; j < 4; ++j)
        out.u[j] = pk2bf(frombf(in.h[2 * j]) * scl, frombf(in.h[2 * j + 1]) * scl);
      qf[ks] = out.v;
    }
  }

  f32x4 oacc[8];
#pragma unroll
  for (int i = 0; i < 8; ++i) oacc[i] = (f32x4){0.f, 0.f, 0.f, 0.f};
  float mrow[4] = {-INFINITY, -INFINITY, -INFINITY, -INFINITY};
  float lrow[4] = {0.f, 0.f, 0.f, 0.f};

  const int ntiles = (kend - kbeg + 63) >> 6;

  bf16x8 kreg[4], vreg[4];
  { // prefetch tile 0
    int kg = kbeg + kkey;
    int kc = kg < Slen ? kg : Slen - 1;
    const uint16_t* ksrc = proj + ((size_t)kc * 8 + b) * 384 + 128 + kcg;
#pragma unroll
    for (int i = 0; i < 4; ++i) kreg[i] = *(const bf16x8*)(ksrc + i * 8);
    const uint16_t* vsrc = Vtb + (((size_t)b * 32 + 11 * split) * 128 + vd) * 64 + vh;
#pragma unroll
    for (int i = 0; i < 4; ++i) vreg[i] = *(const bf16x8*)(vsrc + i * 8);
  }

  for (int kt = 0; kt < ntiles; ++kt) {
    __syncthreads();                     // LDS free (prev compute done)
    { // write staged tile to LDS
      uint16_t* kdst = KsL + kkey * 136 + kcg;
#pragma unroll
      for (int i = 0; i < 4; ++i) *(bf16x8*)(kdst + i * 8) = kreg[i];
      uint16_t* vdst = VtL + vd * 72 + vh;
#pragma unroll
      for (int i = 0; i < 4; ++i) *(bf16x8*)(vdst + i * 8) = vreg[i];
    }
    if (kt + 1 < ntiles) {               // issue next-tile loads (hide under compute)
      int kg = kbeg + (kt + 1) * 64 + kkey;
      int kc = kg < Slen ? kg : Slen - 1;
      const uint16_t* ksrc = proj + ((size_t)kc * 8 + b) * 384 + 128 + kcg;
#pragma unroll
      for (int i = 0; i < 4; ++i) kreg[i] = *(const bf16x8*)(ksrc + i * 8);
      const int tile = 11 * split + kt + 1;
      const uint16_t* vsrc = Vtb + (((size_t)b * 32 + tile) * 128 + vd) * 64 + vh;
#pragma unroll
      for (int i = 0; i < 4; ++i) vreg[i] = *(const bf16x8*)(vsrc + i * 8);
    }
    __syncthreads();                     // LDS ready

    f32x4 sc[4];
#pragma unroll
    for (int nf = 0; nf < 4; ++nf) {
      f32x4 acc = (f32x4){0.f, 0.f, 0.f, 0.f};
#pragma unroll
      for (int ks = 0; ks < 4; ++ks) {
        bf16x8 kf = *(const bf16x8*)(KsL + (size_t)(nf * 16 + ln) * 136 + ks * 32 + qd * 8);
        acc = __builtin_amdgcn_mfma_f32_16x16x32_bf16(qf[ks], kf, acc, 0, 0, 0);
      }
      int key = kbeg + kt * 64 + nf * 16 + ln;
      if (key >= kend) { acc[0] = -1e30f; acc[1] = -1e30f; acc[2] = -1e30f; acc[3] = -1e30f; }
      sc[nf] = acc;
    }

    float alphaR[4];
#pragma unroll
    for (int r = 0; r < 4; ++r) {
      float mx = fmaxf(fmaxf(sc[0][r], sc[1][r]), fmaxf(sc[2][r], sc[3][r]));
      mx = fmaxf(mx, __shfl_xor(mx, 1));
      mx = fmaxf(mx, __shfl_xor(mx, 2));
      mx = fmaxf(mx, __shfl_xor(mx, 4));
      mx = fmaxf(mx, __shfl_xor(mx, 8));
      float mNew = fmaxf(mrow[r], mx);
      float p0 = __expf(sc[0][r] - mNew);
      float p1 = __expf(sc[1][r] - mNew);
      float p2 = __expf(sc[2][r] - mNew);
      float p3 = __expf(sc[3][r] - mNew);
      float ps = p0 + p1 + p2 + p3;
      ps += __shfl_xor(ps, 1);
      ps += __shfl_xor(ps, 2);
      ps += __shfl_xor(ps, 4);
      ps += __shfl_xor(ps, 8);
      float alpha = __expf(mrow[r] - mNew);
      mrow[r] = mNew;
      lrow[r] = lrow[r] * alpha + ps;
      alphaR[r] = alpha;
      uint2 pk;
      pk.x = pk2bf(p0, p1);
      pk.y = pk2bf(p2, p3);
      *(uint2*)(PbL[w] + (size_t)(qd * 4 + r) * 72 + ln * 4) = pk;
    }
#pragma unroll
    for (int no = 0; no < 8; ++no) {
#pragma unroll
      for (int r = 0; r < 4; ++r) oacc[no][r] *= alphaR[r];
    }
    __asm__ volatile("s_waitcnt lgkmcnt(0)" ::: "memory");

#pragma unroll
    for (int ks2 = 0; ks2 < 2; ++ks2) {
      bf16x8 af = *(const bf16x8*)(PbL[w] + (size_t)ln * 72 + ks2 * 32 + qd * 8);
#pragma unroll
      for (int no = 0; no < 8; ++no) {
        bf16x8 vf = *(const bf16x8*)(VtL + (size_t)(no * 16 + ln) * 72 + ks2 * 32 + qd * 8);
        oacc[no] = __builtin_amdgcn_mfma_f32_16x16x32_bf16(af, vf, oacc[no], 0, 0, 0);
      }
    }
  }

#pragma unroll
  for (int r = 0; r < 4; ++r) {
    int qg = q0 + w * 16 + qd * 4 + r;
    if (qg < Slen) {
      size_t row = (size_t)qg * 8 + b;
      float* dst = Opart + ((size_t)split * 16384 + row) * 128 + ln;
#pragma unroll
      for (int no = 0; no < 8; ++no) dst[no * 16] = oacc[no][r];
      if (ln == 0) {
        ml[((size_t)split * 16384 + row) * 2 + 0] = mrow[r];
        ml[((size_t)split * 16384 + row) * 2 + 1] = lrow[r];
      }
    }
  }
}

// ---------------------------------------------------------------------------
// Out-proj GEMM with INLINE split-combine A-staging (reads Opart + ml).
// A[m][k] = (O0*w0 + O1*w1 + O2*w2)*inv, per-row weights precomputed in LDS
// (identical arithmetic to the old combine kernel). HEAD adds the fused
// bpW-dot + sigmoid epilogue; else writes fp32 C (ldc=128).
// ---------------------------------------------------------------------------
template<bool HEAD>
__global__ __launch_bounds__(256) void gemm_attc64(
    const float* __restrict__ Opart, const float* __restrict__ ml,
    const uint16_t* __restrict__ Wb,
    const float* __restrict__ bias,
    const float* __restrict__ bpW, const float* __restrict__ bpb,
    float* __restrict__ out, int M)
{
  __shared__ __align__(16) uint16_t As[64 * 72];
  __shared__ __align__(16) uint16_t Ws[128 * 72];
  __shared__ float RW[64][4];                 // w0,w1,w2,inv per row
  __shared__ float Ct[HEAD ? 64 : 1][133];

  const int K = 128;
  const int t  = threadIdx.x;
  const int m0 = blockIdx.x * 64;
  const int w  = t >> 6, l = t & 63;
  const int ln = l & 15, qd = l >> 4;

  if (t < 64) {
    int m = m0 + t;
    int mc = m < M ? m : M - 1;
    float m0v = ml[(size_t)mc * 2],                 l0 = ml[(size_t)mc * 2 + 1];
    float m1v = ml[((size_t)16384 + mc) * 2],       l1 = ml[((size_t)16384 + mc) * 2 + 1];
    float m2v = ml[((size_t)32768 + mc) * 2],       l2 = ml[((size_t)32768 + mc) * 2 + 1];
    float Mx = fmaxf(fmaxf(m0v, m1v), m2v);
    float w0 = __expf(m0v - Mx), w1 = __expf(m1v - Mx), w2 = __expf(m2v - Mx);
    RW[t][0] = w0; RW[t][1] = w1; RW[t][2] = w2;
    RW[t][3] = 1.f / (l0 * w0 + l1 * w1 + l2 * w2);
  }

  f32x4 acc[4][2];
#pragma unroll
  for (int i = 0; i < 4; ++i) { acc[i][0] = (f32x4){0,0,0,0}; acc[i][1] = (f32x4){0,0,0,0}; }

  const int rr = t >> 4;
  const int cl = (t & 15) * 4;
  const int r8 = t >> 3;
  const int c8 = (t & 7) * 8;

  for (int k0 = 0; k0 < K; k0 += 64) {
    __syncthreads();
#pragma unroll
    for (int i = 0; i < 4; ++i) {
      int m = m0 + rr + 16 * i;
      int mc = m < M ? m : M - 1;
      int kk = k0 + cl;
      float4 a = *(const float4*)(Opart + (size_t)mc * 128 + kk);
      float4 c = *(const float4*)(Opart + ((size_t)16384 + mc) * 128 + kk);
      float4 e = *(const float4*)(Opart + ((size_t)32768 + mc) * 128 + kk);
      int rl = rr + 16 * i;
      float w0 = RW[rl][0], w1 = RW[rl][1], w2 = RW[rl][2], inv = RW[rl][3];
      float4 f = make_float4((a.x * w0 + c.x * w1 + e.x * w2) * inv,
                             (a.y * w0 + c.y * w1 + e.y * w2) * inv,
                             (a.z * w0 + c.z * w1 + e.z * w2) * inv,
                             (a.w * w0 + c.w * w1 + e.w * w2) * inv);
      *(uint2*)(As + (size_t)rl * 72 + cl) = cvt4(f);
    }
#pragma unroll
    for (int i = 0; i < 4; ++i) {
      int n = r8 + 32 * i;
      *(bf16x8*)(Ws + (size_t)n * 72 + c8) =
          *(const bf16x8*)(Wb + (size_t)n * K + k0 + c8);
    }
    __syncthreads();
#pragma unroll
    for (int ks = 0; ks < 2; ++ks) {
      bf16x8 af[4], bfr[2];
#pragma unroll
      for (int mf = 0; mf < 4; ++mf)
        af[mf] = *(const bf16x8*)(As + (size_t)(mf * 16 + ln) * 72 + ks * 32 + qd * 8);
#pragma unroll
      for (int nf = 0; nf < 2; ++nf)
        bfr[nf] = *(const bf16x8*)(Ws + (size_t)(w * 32 + nf * 16 + ln) * 72 + ks * 32 + qd * 8);
#pragma unroll
      for (int mf = 0; mf < 4; ++mf)
#pragma unroll
        for (int nf = 0; nf < 2; ++nf)
          acc[mf][nf] = __builtin_amdgcn_mfma_f32_16x16x32_bf16(af[mf], bfr[nf], acc[mf][nf], 0, 0, 0);
    }
  }

  if (HEAD) {
    __syncthreads();
#pragma unroll
    for (int mf = 0; mf < 4; ++mf) {
#pragma unroll
      for (int r = 0; r < 4; ++r) {
        int rowL = mf * 16 + qd * 4 + r;
#pragma unroll
        for (int nf = 0; nf < 2; ++nf) {
          int n = w * 32 + nf * 16 + ln;
          Ct[rowL][n] = acc[mf][nf][r] + bias[n];
        }
      }
    }
    __syncthreads();
    int row = t >> 2, qg = t & 3;
    int m = m0 + row;
    float p = 0.f;
#pragma unroll
    for (int j = 0; j < 32; ++j) {
      int c = qg + j * 4;
      p += Ct[row][c] * bpW[c];
    }
    p += __shfl_xor(p, 1);
    p += __shfl_xor(p, 2);
    if (qg == 0 && m < M)
      out[m] = 1.f / (1.f + __expf(-(p + bpb[0])));
  } else {
#pragma unroll
    for (int mf = 0; mf < 4; ++mf) {
#pragma unroll
      for (int r = 0; r < 4; ++r) {
        int m = m0 + mf * 16 + qd * 4 + r;
        if (m < M) {
#pragma unroll
          for (int nf = 0; nf < 2; ++nf) {
            int n = w * 32 + nf * 16 + ln;
            out[(size_t)m * 128 + n] = acc[mf][nf][r] + bias[n];
          }
        }
      }
    }
  }
}

// ---------------------------------------------------------------------------
// Cumsum over s of e (S,B,128): 64 chunks x 32 rows (512 blocks p1).
// ---------------------------------------------------------------------------
__global__ void cumsum_p1(const float* __restrict__ e, float* __restrict__ csum,
                          float* __restrict__ part)
{
  int chunk = blockIdx.x, b = blockIdx.y, d = threadIdx.x;
  float run = 0.f;
  int s0 = chunk * 32;
  for (int s = 0; s < 32; ++s) {
    size_t idx = ((size_t)(s0 + s) * 8 + b) * 128 + d;
    run += e[idx];
    csum[idx] = run;
  }
  part[(b * 64 + chunk) * 128 + d] = run;
}

__global__ void cumsum_p2(float* __restrict__ part)
{
  int b = blockIdx.x, d = threadIdx.x;
  float run = 0.f;
  for (int c = 0; c < 64; ++c) {
    float v = part[(b * 64 + c) * 128 + d];
    part[(b * 64 + c) * 128 + d] = run;
    run += v;
  }
}

// ---------------------------------------------------------------------------
extern "C" void kernel_launch(void* const* d_in, const int* in_sizes, int n_in,
                              void* d_out, int out_size, void* d_ws, size_t ws_size,
                              hipStream_t stream)
{
  const float* x       = (const float*)d_in[0];
  const float* pW      = (const float*)d_in[1];
  const float* pb      = (const float*)d_in[2];
  const float* cW      = (const float*)d_in[3];
  const float* cb      = (const float*)d_in[4];
  const float* aW      = (const float*)d_in[5];
  const float* ab      = (const float*)d_in[6];
  const float* uW      = (const float*)d_in[7];
  const float* ub      = (const float*)d_in[8];
  const float* eW      = (const float*)d_in[9];
  const float* eb      = (const float*)d_in[10];
  const float* la_win  = (const float*)d_in[11];
  const float* la_bin  = (const float*)d_in[12];
  const float* la_wout = (const float*)d_in[13];
  const float* la_bout = (const float*)d_in[14];
  const float* beW     = (const float*)d_in[15];
  const float* beb     = (const float*)d_in[16];
  const float* ba_win  = (const float*)d_in[17];
  const float* ba_bin  = (const float*)d_in[18];
  const float* ba_wout = (const float*)d_in[19];
  const float* ba_bout = (const float*)d_in[20];
  const float* bpW     = (const float*)d_in[21];
  const float* bpb     = (const float*)d_in[22];

  float* ws   = (float*)d_ws;
  float* outF = (float*)d_out;

  // Workspace plan (float offsets):
  //  [0, 344064)                WB: bf16 weights
  //  M0=344064:
  //  [M0, +4,194,304)           feats bf16 (dead after e0) / csum fp32
  //  [M0+2,097,152, +65,536)    partB (coexists only with csum)
  //  [M0+4,194,304, +1,048,576) e0 / b0 bf16 (serial)
  //  [M0+5,242,880, +3,145,728) proj bf16 (alive through attention)
  //  [M0+8,388,608, +1,048,576) Vtb bf16
  //  [M0+9,437,184, +6,291,456) Opart fp32 (3 splits)
  //  [M0+15,728,640, +98,304)   ml (3 splits)
  uint16_t* WB  = (uint16_t*)ws;
  float* base   = ws + 344064;
  uint16_t* featsB = (uint16_t*)base;
  float* csumB  = base;
  float* partB  = base + 2097152;
  uint16_t* eB  = (uint16_t*)(base + 4194304);   // e0 / b0
  uint16_t* projB = (uint16_t*)(base + 5242880);
  uint16_t* VtbB  = (uint16_t*)(base + 8388608);
  float* OpartB = base + 9437184;
  float* mlB    = base + 15728640;

  // 0. weights -> bf16
  WPtrs wp;
  wp.p[0] = pW; wp.p[1] = cW; wp.p[2] = aW; wp.p[3] = uW; wp.p[4] = eW;
  wp.p[5] = la_win; wp.p[6] = la_wout; wp.p[7] = beW; wp.p[8] = ba_win; wp.p[9] = ba_wout;
  pack_weights<<<dim3(672), 256, 0, stream>>>(wp, WB);

  // 1. feats = relu(segment linears) -> bf16
  gemm_feats64<<<dim3(256, 4), 256, 0, stream>>>(x, WB, pb, cb, ab, ub, featsB);
  // 2. e0 = relu(feats @ eW^T + eb) -> bf16, remapped (B,S)->(S,B)
  gemm64<true, true, true, true><<<dim3(256, 1), 256, 0, stream>>>(
      featsB, 512, WB + OFF_EW, eb, eB, 128, 16384, 512);
  // 3. proj1 = e0 @ la_win^T + la_bin -> bf16
  gemm64<true, true, false, false><<<dim3(256, 3), 256, 0, stream>>>(
      eB, 128, WB + OFF_LAWIN, la_bin, projB, 384, 16384, 128);
  // 4. V pack + 3-split flash
  vpack<<<dim3(32, 8), 256, 0, stream>>>(projB, VtbB, 2048);
  attn_split3<<<dim3(32, 8, 3), 256, 0, stream>>>(projB, VtbB, OpartB, mlB, 2048);
  // 5. e = combine(att1) @ la_wout^T + la_bout -> d_out (fp32), combine inlined
  gemm_attc64<false><<<dim3(256), 256, 0, stream>>>(
      OpartB, mlB, WB + OFF_LAWOUT, la_bout, nullptr, nullptr, outF, 16384);
  // 6-7. csum (local prefixes + chunk offsets; p3 fused into becat)
  cumsum_p1<<<dim3(64, 8), 128, 0, stream>>>(outF, csumB, partB);
  cumsum_p2<<<dim3(8), 128, 0, stream>>>(partB);
  // 8. b0 = relu(cat(left,right) @ beW^T + beb) -> bf16
  gemm_becat64<<<dim3(256), 256, 0, stream>>>(csumB, partB, WB + OFF_BEW, beb, eB);
  // 9. proj2
  gemm64<true, true, false, false><<<dim3(256, 3), 256, 0, stream>>>(
      eB, 128, WB + OFF_BAWIN, ba_bin, projB, 384, 16376, 128);
  // 10. V pack + att2 (Slen = 2047)
  vpack<<<dim3(32, 8), 256, 0, stream>>>(projB, VtbB, 2047);
  attn_split3<<<dim3(32, 8, 3), 256, 0, stream>>>(projB, VtbB, OpartB, mlB, 2047);
  // 11. bout GEMM: combine inlined + fused sigmoid head -> d_out tail
  gemm_attc64<true><<<dim3(256), 256, 0, stream>>>(
      OpartB, mlB, WB + OFF_BAWOUT, ba_bout, bpW, bpb, outF + 2097152, 16376);
}

// Round 5
// 519.308 us; speedup vs baseline: 1.3010x; 1.0345x over previous
//
#include <hip/hip_runtime.h>
#include <hip/hip_bf16.h>
#include <math.h>
#include <stdint.h>

// ---------------------------------------------------------------------------
// SceneSegmenter Round 9: swapped-QK^T attention round.
//  - attn_split3: mfma(K,Q) so each lane owns one q-row's scores for 16 keys.
//    Softmax = in-lane reduce + 2 shuffles; P repacked in-register straight
//    into the PV A-fragment (PbL LDS buffer + lgkm wait deleted).
//  - vpack permutation re-derived to match the in-register P fragment order:
//    u32 slot u holds keys K,K+1 with K = 32(u>>4)+16((u>>1)&1)+4((u>>2)&3)+2(u&1).
//  - Everything else identical to the passing Round-8 kernel.
// Layouts: token-major activations (S, B, D) flat, row = s*8+b.
// ---------------------------------------------------------------------------

#define DEV static __device__ __forceinline__

typedef __attribute__((ext_vector_type(8))) short bf16x8;   // 8 bf16 (4 VGPRs)
typedef __attribute__((ext_vector_type(4))) float f32x4;    // MFMA C/D

DEV uint32_t pk2bf(float a, float b) {       // packed fp32x2 -> bf16x2 (RNE)
  __hip_bfloat162 h = __float22bfloat162_rn(make_float2(a, b));
  return *(uint32_t*)&h;
}
DEV uint2 cvt4(float4 f) {                   // 4 fp32 -> 4 bf16
  return make_uint2(pk2bf(f.x, f.y), pk2bf(f.z, f.w));
}
DEV uint16_t bf1(float a) { return (uint16_t)(pk2bf(a, 0.f) & 0xffffu); }
DEV float frombf(uint16_t h) {
  union { uint32_t u; float f; } v; v.u = ((uint32_t)h) << 16; return v.f;
}

// Weight-pack offsets (halves) inside WB
#define OFF_PW      0u
#define OFF_CW      262144u
#define OFF_AW      327680u
#define OFF_UW      393216u
#define OFF_EW      458752u
#define OFF_LAWIN   524288u
#define OFF_LAWOUT  573440u
#define OFF_BEW     589824u
#define OFF_BAWIN   622592u
#define OFF_BAWOUT  671744u
#define OFF_END     688128u

struct WPtrs { const float* p[10]; };

// ---------------------------------------------------------------------------
// pack_weights: concatenated fp32 weights -> bf16 WB. 672 blocks x 256 thr.
// ---------------------------------------------------------------------------
__global__ __launch_bounds__(256) void pack_weights(WPtrs wp, uint16_t* __restrict__ WB)
{
  const uint32_t off[11] = {OFF_PW, OFF_CW, OFF_AW, OFF_UW, OFF_EW, OFF_LAWIN,
                            OFF_LAWOUT, OFF_BEW, OFF_BAWIN, OFF_BAWOUT, OFF_END};
  uint32_t h = (blockIdx.x * 256u + threadIdx.x) * 4u;
  if (h >= OFF_END) return;
  int s = 0;
  while (h >= off[s + 1]) ++s;
  float4 f = *(const float4*)(wp.p[s] + (h - off[s]));
  *(uint2*)(WB + h) = cvt4(f);
}

// ---------------------------------------------------------------------------
// Templated bf16 MFMA GEMM, BM=64 x BN=128, BK=64, 256 thr = 4 waves.
// ---------------------------------------------------------------------------
template<bool ABF, bool OBF, bool RELU, bool REMAP>
__global__ __launch_bounds__(256) void gemm64(
    const void* __restrict__ Ap, int lda,
    const uint16_t* __restrict__ Wb,
    const float* __restrict__ bias,
    void* __restrict__ Cp, int ldc,
    int M, int K)
{
  __shared__ __align__(16) uint16_t As[64 * 72];
  __shared__ __align__(16) uint16_t Ws[128 * 72];

  const int t  = threadIdx.x;
  const int m0 = blockIdx.x * 64;
  const int n0 = blockIdx.y * 128;
  const int w  = t >> 6, l = t & 63;
  const int ln = l & 15, qd = l >> 4;

  f32x4 acc[4][2];
#pragma unroll
  for (int i = 0; i < 4; ++i) { acc[i][0] = (f32x4){0,0,0,0}; acc[i][1] = (f32x4){0,0,0,0}; }

  const int rr = t >> 4;          // fp32-A path: 16 rows
  const int cl = (t & 15) * 4;
  const int r8 = t >> 3;          // bf16 paths: 32 rows
  const int c8 = (t & 7) * 8;     // half col (16B)

  for (int k0 = 0; k0 < K; k0 += 64) {
    __syncthreads();
    if (ABF) {
      const uint16_t* A = (const uint16_t*)Ap;
#pragma unroll
      for (int i = 0; i < 2; ++i) {
        int m = m0 + r8 + 32 * i;
        int mc = m < M ? m : M - 1;
        *(bf16x8*)(As + (size_t)(r8 + 32 * i) * 72 + c8) =
            *(const bf16x8*)(A + (size_t)mc * lda + k0 + c8);
      }
    } else {
      const float* A = (const float*)Ap;
#pragma unroll
      for (int i = 0; i < 4; ++i) {
        int m = m0 + rr + 16 * i;
        int mc = m < M ? m : M - 1;
        float4 f = *(const float4*)(A + (size_t)mc * lda + k0 + cl);
        *(uint2*)(As + (size_t)(rr + 16 * i) * 72 + cl) = cvt4(f);
      }
    }
#pragma unroll
    for (int i = 0; i < 4; ++i) {           // W tile: 128 rows, pure copy
      int n = r8 + 32 * i;
      *(bf16x8*)(Ws + (size_t)n * 72 + c8) =
          *(const bf16x8*)(Wb + (size_t)(n0 + n) * K + k0 + c8);
    }
    __syncthreads();
#pragma unroll
    for (int ks = 0; ks < 2; ++ks) {
      bf16x8 af[4], bfr[2];
#pragma unroll
      for (int mf = 0; mf < 4; ++mf)
        af[mf] = *(const bf16x8*)(As + (size_t)(mf * 16 + ln) * 72 + ks * 32 + qd * 8);
#pragma unroll
      for (int nf = 0; nf < 2; ++nf)
        bfr[nf] = *(const bf16x8*)(Ws + (size_t)(w * 32 + nf * 16 + ln) * 72 + ks * 32 + qd * 8);
#pragma unroll
      for (int mf = 0; mf < 4; ++mf)
#pragma unroll
        for (int nf = 0; nf < 2; ++nf)
          acc[mf][nf] = __builtin_amdgcn_mfma_f32_16x16x32_bf16(af[mf], bfr[nf], acc[mf][nf], 0, 0, 0);
    }
  }

#pragma unroll
  for (int mf = 0; mf < 4; ++mf) {
#pragma unroll
    for (int r = 0; r < 4; ++r) {
      int m = m0 + mf * 16 + qd * 4 + r;
      if (m < M) {
        size_t ro = REMAP ? (size_t)((m & 2047) * 8 + (m >> 11)) : (size_t)m;
#pragma unroll
        for (int nf = 0; nf < 2; ++nf) {
          int n = n0 + w * 32 + nf * 16 + ln;
          float v = acc[mf][nf][r] + bias[n];
          if (RELU) v = fmaxf(v, 0.f);
          if (OBF) ((uint16_t*)Cp)[ro * (size_t)ldc + n] = bf1(v);
          else     ((float*)Cp)[ro * (size_t)ldc + n] = v;
        }
      }
    }
  }
}

// ---------------------------------------------------------------------------
// Fused 4-segment feats GEMM (A = x fp32, W bf16 pre-packed, out bf16).
// ---------------------------------------------------------------------------
__global__ __launch_bounds__(256) void gemm_feats64(
    const float* __restrict__ x, const uint16_t* __restrict__ WB,
    const float* __restrict__ pb, const float* __restrict__ cb,
    const float* __restrict__ ab, const float* __restrict__ ub,
    uint16_t* __restrict__ feats)
{
  __shared__ __align__(16) uint16_t As[64 * 72];
  __shared__ __align__(16) uint16_t Ws[128 * 72];

  const int seg = blockIdx.y;
  const uint16_t* Wb; const float* bias; int kbase, Kseg;
  if (seg == 0)      { Wb = WB + OFF_PW; bias = pb; kbase = 0;    Kseg = 2048; }
  else if (seg == 1) { Wb = WB + OFF_CW; bias = cb; kbase = 2048; Kseg = 512; }
  else if (seg == 2) { Wb = WB + OFF_AW; bias = ab; kbase = 2560; Kseg = 512; }
  else               { Wb = WB + OFF_UW; bias = ub; kbase = 3072; Kseg = 512; }

  const int t  = threadIdx.x;
  const int m0 = blockIdx.x * 64;
  const int w  = t >> 6, l = t & 63;
  const int ln = l & 15, qd = l >> 4;

  f32x4 acc[4][2];
#pragma unroll
  for (int i = 0; i < 4; ++i) { acc[i][0] = (f32x4){0,0,0,0}; acc[i][1] = (f32x4){0,0,0,0}; }

  const int rr = t >> 4;
  const int cl = (t & 15) * 4;
  const int r8 = t >> 3;
  const int c8 = (t & 7) * 8;

  for (int k0 = 0; k0 < Kseg; k0 += 64) {
    __syncthreads();
#pragma unroll
    for (int i = 0; i < 4; ++i) {
      int m = m0 + rr + 16 * i;
      float4 f = *(const float4*)(x + (size_t)m * 3584 + kbase + k0 + cl);
      *(uint2*)(As + (size_t)(rr + 16 * i) * 72 + cl) = cvt4(f);
    }
#pragma unroll
    for (int i = 0; i < 4; ++i) {
      int n = r8 + 32 * i;
      *(bf16x8*)(Ws + (size_t)n * 72 + c8) =
          *(const bf16x8*)(Wb + (size_t)n * Kseg + k0 + c8);
    }
    __syncthreads();
#pragma unroll
    for (int ks = 0; ks < 2; ++ks) {
      bf16x8 af[4], bfr[2];
#pragma unroll
      for (int mf = 0; mf < 4; ++mf)
        af[mf] = *(const bf16x8*)(As + (size_t)(mf * 16 + ln) * 72 + ks * 32 + qd * 8);
#pragma unroll
      for (int nf = 0; nf < 2; ++nf)
        bfr[nf] = *(const bf16x8*)(Ws + (size_t)(w * 32 + nf * 16 + ln) * 72 + ks * 32 + qd * 8);
#pragma unroll
      for (int mf = 0; mf < 4; ++mf)
#pragma unroll
        for (int nf = 0; nf < 2; ++nf)
          acc[mf][nf] = __builtin_amdgcn_mfma_f32_16x16x32_bf16(af[mf], bfr[nf], acc[mf][nf], 0, 0, 0);
    }
  }

#pragma unroll
  for (int mf = 0; mf < 4; ++mf) {
#pragma unroll
    for (int r = 0; r < 4; ++r) {
      int m = m0 + mf * 16 + qd * 4 + r;
#pragma unroll
      for (int nf = 0; nf < 2; ++nf) {
        int n = w * 32 + nf * 16 + ln;
        float v = fmaxf(acc[mf][nf][r] + bias[n], 0.f);
        feats[(size_t)m * 512 + seg * 128 + n] = bf1(v);
      }
    }
  }
}

// ---------------------------------------------------------------------------
// becat GEMM with fused cumsum chunk-offset (p3): b0 = relu(cat @ beW^T + b).
// ---------------------------------------------------------------------------
__global__ __launch_bounds__(256) void gemm_becat64(
    const float* __restrict__ csum, const float* __restrict__ part,
    const uint16_t* __restrict__ Wb, const float* __restrict__ bias,
    uint16_t* __restrict__ C)
{
  __shared__ __align__(16) uint16_t As[64 * 72];
  __shared__ __align__(16) uint16_t Ws[128 * 72];

  const int M = 16376, K = 256;
  const int t  = threadIdx.x;
  const int m0 = blockIdx.x * 64;
  const int w  = t >> 6, l = t & 63;
  const int ln = l & 15, qd = l >> 4;

  f32x4 acc[4][2];
#pragma unroll
  for (int i = 0; i < 4; ++i) { acc[i][0] = (f32x4){0,0,0,0}; acc[i][1] = (f32x4){0,0,0,0}; }

  const int rr = t >> 4;
  const int cl = (t & 15) * 4;
  const int r8 = t >> 3;
  const int c8 = (t & 7) * 8;

  for (int k0 = 0; k0 < K; k0 += 64) {
    __syncthreads();
#pragma unroll
    for (int i = 0; i < 4; ++i) {
      int m = m0 + rr + 16 * i;
      int mc = m < M ? m : M - 1;
      int j = mc >> 3, bb = mc & 7;
      int kk = k0 + cl;
      float4 f;
      if (kk < 128) {
        float4 v = *(const float4*)(csum + (size_t)mc * 128 + kk);
        float4 p = *(const float4*)(part + (size_t)(bb * 64 + (j >> 5)) * 128 + kk);
        float s = 1.f / (float)(j + 1);
        f = make_float4((v.x + p.x) * s, (v.y + p.y) * s,
                        (v.z + p.z) * s, (v.w + p.w) * s);
      } else {
        int d = kk - 128;
        float4 c0 = *(const float4*)(csum + (size_t)mc * 128 + d);
        float4 p0 = *(const float4*)(part + (size_t)(bb * 64 + (j >> 5)) * 128 + d);
        float4 ct = *(const float4*)(csum + (size_t)(16376 + bb) * 128 + d);
        float4 pt = *(const float4*)(part + (size_t)(bb * 64 + 63) * 128 + d);
        float s = 1.f / (float)(2047 - j);
        f = make_float4(((ct.x + pt.x) - (c0.x + p0.x)) * s,
                        ((ct.y + pt.y) - (c0.y + p0.y)) * s,
                        ((ct.z + pt.z) - (c0.z + p0.z)) * s,
                        ((ct.w + pt.w) - (c0.w + p0.w)) * s);
      }
      *(uint2*)(As + (size_t)(rr + 16 * i) * 72 + cl) = cvt4(f);
    }
#pragma unroll
    for (int i = 0; i < 4; ++i) {
      int n = r8 + 32 * i;
      *(bf16x8*)(Ws + (size_t)n * 72 + c8) =
          *(const bf16x8*)(Wb + (size_t)n * K + k0 + c8);
    }
    __syncthreads();
#pragma unroll
    for (int ks = 0; ks < 2; ++ks) {
      bf16x8 af[4], bfr[2];
#pragma unroll
      for (int mf = 0; mf < 4; ++mf)
        af[mf] = *(const bf16x8*)(As + (size_t)(mf * 16 + ln) * 72 + ks * 32 + qd * 8);
#pragma unroll
      for (int nf = 0; nf < 2; ++nf)
        bfr[nf] = *(const bf16x8*)(Ws + (size_t)(w * 32 + nf * 16 + ln) * 72 + ks * 32 + qd * 8);
#pragma unroll
      for (int mf = 0; mf < 4; ++mf)
#pragma unroll
        for (int nf = 0; nf < 2; ++nf)
          acc[mf][nf] = __builtin_amdgcn_mfma_f32_16x16x32_bf16(af[mf], bfr[nf], acc[mf][nf], 0, 0, 0);
    }
  }

#pragma unroll
  for (int mf = 0; mf < 4; ++mf) {
#pragma unroll
    for (int r = 0; r < 4; ++r) {
      int m = m0 + mf * 16 + qd * 4 + r;
      if (m < M) {
#pragma unroll
        for (int nf = 0; nf < 2; ++nf) {
          int n = w * 32 + nf * 16 + ln;
          C[(size_t)m * 128 + n] = bf1(fmaxf(acc[mf][nf][r] + bias[n], 0.f));
        }
      }
    }
  }
}

// ---------------------------------------------------------------------------
// vpack: V third of bf16 proj -> Vtb [b][tile32][d128][key64].
// u32 slot u (0..31) of a d-row holds keys K,K+1 with
//   K = 32*(u>>4) + 16*((u>>1)&1) + 4*((u>>2)&3) + 2*(u&1)
// matching the attention kernel's in-register P fragment order.
// ---------------------------------------------------------------------------
__global__ __launch_bounds__(256) void vpack(
    const uint16_t* __restrict__ proj, uint16_t* __restrict__ Vtb, int Slen)
{
  __shared__ __align__(16) uint16_t Vs[64][136];

  const int kt = blockIdx.x, b = blockIdx.y, t = threadIdx.x;
  const int sl = t >> 2, cg = (t & 3) * 32;
  const int s  = kt * 64 + sl;
  const int valid = s < Slen;
  const int sc2 = valid ? s : Slen - 1;
  const uint16_t* src = proj + ((size_t)sc2 * 8 + b) * 384 + 256 + cg;
#pragma unroll
  for (int i = 0; i < 4; ++i) {
    bf16x8 v;
    if (valid) v = *(const bf16x8*)(src + i * 8);
    else       v = (bf16x8){0,0,0,0,0,0,0,0};
    *(bf16x8*)(&Vs[sl][cg + i * 8]) = v;
  }
  __syncthreads();
  const int d = t >> 1, hh = t & 1;     // hh = ks2 half (keys 32hh..32hh+31)
  uint32_t wv[16];
#pragma unroll
  for (int i = 0; i < 16; ++i) {
    int K = 32 * hh + 16 * ((i >> 1) & 1) + 4 * ((i >> 2) & 3) + 2 * (i & 1);
    wv[i] = (uint32_t)Vs[K][d] | ((uint32_t)Vs[K + 1][d] << 16);
  }
  uint16_t* dv = Vtb + (((size_t)b * 32 + kt) * 128 + d) * 64 + hh * 32;
#pragma unroll
  for (int i = 0; i < 4; ++i)
    *(uint4*)(dv + i * 8) = *(uint4*)(&wv[i * 4]);
}

// ---------------------------------------------------------------------------
// 3-way split-K flash attention, swapped QK^T: acc = mfma(K, Q) so lane
// holds S^T[key][q=ln]. Softmax = in-lane 16-reduce + 2 shuffles; P repacked
// in-register into the PV A-fragment (no P LDS buffer). T14 prefetch kept.
// ---------------------------------------------------------------------------
__global__ __launch_bounds__(256, 3) void attn_split3(
    const uint16_t* __restrict__ proj, const uint16_t* __restrict__ Vtb,
    float* __restrict__ Opart, float* __restrict__ ml, int Slen)
{
  __shared__ __align__(16) uint16_t KsL[64 * 136];     // [key][k], pitch 136
  __shared__ __align__(16) uint16_t VtL[128 * 72];     // [d][k'],  pitch 72

  const int t  = threadIdx.x;
  const int b  = blockIdx.y;
  const int q0 = blockIdx.x * 64;
  const int split = blockIdx.z;
  const int kbeg = split * 704;
  const int kend = (split == 2) ? Slen : kbeg + 704;
  const int w  = t >> 6;
  const int l  = t & 63;
  const int ln = l & 15;
  const int qd = l >> 4;
  const float scl = 0.08838834764831845f;   // 1/sqrt(128)

  const int kkey = t >> 2, kcg = (t & 3) * 32;   // K staging map
  const int vd   = t >> 1, vh  = (t & 1) * 32;   // V staging map

  bf16x8 qf[4];
  {
    int qrow = q0 + w * 16 + ln;
    int qc = qrow < Slen ? qrow : Slen - 1;
    const uint16_t* qp = proj + ((size_t)qc * 8 + b) * 384 + qd * 8;
#pragma unroll
    for (int ks = 0; ks < 4; ++ks) {
      union { bf16x8 v; uint16_t h[8]; uint32_t u[4]; } in, out;
      in.v = *(const bf16x8*)(qp + ks * 32);
#pragma unroll
      for (int j = 0; j < 4; ++j)
        out.u[j] = pk2bf(frombf(in.h[2 * j]) * scl, frombf(in.h[2 * j + 1]) * scl);
      qf[ks] = out.v;
    }
  }

  f32x4 oacc[8];
#pragma unroll
  for (int i = 0; i < 8; ++i) oacc[i] = (f32x4){0.f, 0.f, 0.f, 0.f};
  float mrow = -INFINITY;          // per-lane: q = q0 + w*16 + ln
  float lrow = 0.f;

  const int ntiles = (kend - kbeg + 63) >> 6;

  bf16x8 kreg[4], vreg[4];
  { // prefetch tile 0
    int kg = kbeg + kkey;
    int kc = kg < Slen ? kg : Slen - 1;
    const uint16_t* ksrc = proj + ((size_t)kc * 8 + b) * 384 + 128 + kcg;
#pragma unroll
    for (int i = 0; i < 4; ++i) kreg[i] = *(const bf16x8*)(ksrc + i * 8);
    const uint16_t* vsrc = Vtb + (((size_t)b * 32 + 11 * split) * 128 + vd) * 64 + vh;
#pragma unroll
    for (int i = 0; i < 4; ++i) vreg[i] = *(const bf16x8*)(vsrc + i * 8);
  }

  for (int kt = 0; kt < ntiles; ++kt) {
    __syncthreads();                     // LDS free (prev compute done)
    { // write staged tile to LDS
      uint16_t* kdst = KsL + kkey * 136 + kcg;
#pragma unroll
      for (int i = 0; i < 4; ++i) *(bf16x8*)(kdst + i * 8) = kreg[i];
      uint16_t* vdst = VtL + vd * 72 + vh;
#pragma unroll
      for (int i = 0; i < 4; ++i) *(bf16x8*)(vdst + i * 8) = vreg[i];
    }
    if (kt + 1 < ntiles) {               // issue next-tile loads (hide under compute)
      int kg = kbeg + (kt + 1) * 64 + kkey;
      int kc = kg < Slen ? kg : Slen - 1;
      const uint16_t* ksrc = proj + ((size_t)kc * 8 + b) * 384 + 128 + kcg;
#pragma unroll
      for (int i = 0; i < 4; ++i) kreg[i] = *(const bf16x8*)(ksrc + i * 8);
      const int tile = 11 * split + kt + 1;
      const uint16_t* vsrc = Vtb + (((size_t)b * 32 + tile) * 128 + vd) * 64 + vh;
#pragma unroll
      for (int i = 0; i < 4; ++i) vreg[i] = *(const bf16x8*)(vsrc + i * 8);
    }
    __syncthreads();                     // LDS ready

    // QK^T swapped: lane holds S[key = nf*16 + qd*4 + r][q = ln]
    float sc[4][4];
#pragma unroll
    for (int nf = 0; nf < 4; ++nf) {
      f32x4 acc = (f32x4){0.f, 0.f, 0.f, 0.f};
#pragma unroll
      for (int ks = 0; ks < 4; ++ks) {
        bf16x8 kf = *(const bf16x8*)(KsL + (size_t)(nf * 16 + ln) * 136 + ks * 32 + qd * 8);
        acc = __builtin_amdgcn_mfma_f32_16x16x32_bf16(kf, qf[ks], acc, 0, 0, 0);
      }
      int keyb = kbeg + kt * 64 + nf * 16 + qd * 4;
#pragma unroll
      for (int r = 0; r < 4; ++r)
        sc[nf][r] = (keyb + r < kend) ? acc[r] : -1e30f;
    }

    // online softmax: in-lane 16-max + 2 shuffles
    float mx = sc[0][0];
#pragma unroll
    for (int nf = 0; nf < 4; ++nf)
#pragma unroll
      for (int r = 0; r < 4; ++r) mx = fmaxf(mx, sc[nf][r]);
    mx = fmaxf(mx, __shfl_xor(mx, 16));
    mx = fmaxf(mx, __shfl_xor(mx, 32));
    float mNew = fmaxf(mrow, mx);

    float ps = 0.f;
#pragma unroll
    for (int nf = 0; nf < 4; ++nf) {
      float p0 = __expf(sc[nf][0] - mNew);
      float p1 = __expf(sc[nf][1] - mNew);
      float p2 = __expf(sc[nf][2] - mNew);
      float p3 = __expf(sc[nf][3] - mNew);
      sc[nf][0] = p0; sc[nf][1] = p1; sc[nf][2] = p2; sc[nf][3] = p3;
      ps += (p0 + p1) + (p2 + p3);
    }
    ps += __shfl_xor(ps, 16);
    ps += __shfl_xor(ps, 32);

    float alpha = __expf(mrow - mNew);
    mrow = mNew;
    lrow = lrow * alpha + ps;

    // alpha for the lane's OUTPUT rows q' = qd*4 + r (bpermute within group)
    float alphaR[4];
#pragma unroll
    for (int r = 0; r < 4; ++r)
      alphaR[r] = __shfl(alpha, (l & 48) | (qd * 4 + r));
#pragma unroll
    for (int no = 0; no < 8; ++no) {
#pragma unroll
      for (int r = 0; r < 4; ++r) oacc[no][r] *= alphaR[r];
    }

    // in-register P -> PV A-fragments (order matches vpack permutation)
    union { bf16x8 v; uint32_t u[4]; } pa0, pa1;
#pragma unroll
    for (int i = 0; i < 4; ++i) {
      pa0.u[i] = pk2bf(sc[(i >> 1)][(i & 1) * 2],     sc[(i >> 1)][(i & 1) * 2 + 1]);
      pa1.u[i] = pk2bf(sc[2 + (i >> 1)][(i & 1) * 2], sc[2 + (i >> 1)][(i & 1) * 2 + 1]);
    }
#pragma unroll
    for (int no = 0; no < 8; ++no) {
      bf16x8 vf = *(const bf16x8*)(VtL + (size_t)(no * 16 + ln) * 72 + qd * 8);
      oacc[no] = __builtin_amdgcn_mfma_f32_16x16x32_bf16(pa0.v, vf, oacc[no], 0, 0, 0);
    }
#pragma unroll
    for (int no = 0; no < 8; ++no) {
      bf16x8 vf = *(const bf16x8*)(VtL + (size_t)(no * 16 + ln) * 72 + 32 + qd * 8);
      oacc[no] = __builtin_amdgcn_mfma_f32_16x16x32_bf16(pa1.v, vf, oacc[no], 0, 0, 0);
    }
  }

  // store unnormalized partials + (m, l)
#pragma unroll
  for (int r = 0; r < 4; ++r) {
    int qg = q0 + w * 16 + qd * 4 + r;
    if (qg < Slen) {
      size_t row = (size_t)qg * 8 + b;
      float* dst = Opart + ((size_t)split * 16384 + row) * 128 + ln;
#pragma unroll
      for (int no = 0; no < 8; ++no) dst[no * 16] = oacc[no][r];
    }
  }
  {
    int qg = q0 + w * 16 + ln;
    if (qd == 0 && qg < Slen) {
      size_t row = (size_t)qg * 8 + b;
      ml[((size_t)split * 16384 + row) * 2 + 0] = mrow;
      ml[((size_t)split * 16384 + row) * 2 + 1] = lrow;
    }
  }
}

// ---------------------------------------------------------------------------
// Out-proj GEMM with INLINE split-combine A-staging (reads Opart + ml).
// ---------------------------------------------------------------------------
template<bool HEAD>
__global__ __launch_bounds__(256) void gemm_attc64(
    const float* __restrict__ Opart, const float* __restrict__ ml,
    const uint16_t* __restrict__ Wb,
    const float* __restrict__ bias,
    const float* __restrict__ bpW, const float* __restrict__ bpb,
    float* __restrict__ out, int M)
{
  __shared__ __align__(16) uint16_t As[64 * 72];
  __shared__ __align__(16) uint16_t Ws[128 * 72];
  __shared__ float RW[64][4];                 // w0,w1,w2,inv per row
  __shared__ float Ct[HEAD ? 64 : 1][133];

  const int K = 128;
  const int t  = threadIdx.x;
  const int m0 = blockIdx.x * 64;
  const int w  = t >> 6, l = t & 63;
  const int ln = l & 15, qd = l >> 4;

  if (t < 64) {
    int m = m0 + t;
    int mc = m < M ? m : M - 1;
    float m0v = ml[(size_t)mc * 2],                 l0 = ml[(size_t)mc * 2 + 1];
    float m1v = ml[((size_t)16384 + mc) * 2],       l1 = ml[((size_t)16384 + mc) * 2 + 1];
    float m2v = ml[((size_t)32768 + mc) * 2],       l2 = ml[((size_t)32768 + mc) * 2 + 1];
    float Mx = fmaxf(fmaxf(m0v, m1v), m2v);
    float w0 = __expf(m0v - Mx), w1 = __expf(m1v - Mx), w2 = __expf(m2v - Mx);
    RW[t][0] = w0; RW[t][1] = w1; RW[t][2] = w2;
    RW[t][3] = 1.f / (l0 * w0 + l1 * w1 + l2 * w2);
  }

  f32x4 acc[4][2];
#pragma unroll
  for (int i = 0; i < 4; ++i) { acc[i][0] = (f32x4){0,0,0,0}; acc[i][1] = (f32x4){0,0,0,0}; }

  const int rr = t >> 4;
  const int cl = (t & 15) * 4;
  const int r8 = t >> 3;
  const int c8 = (t & 7) * 8;

  for (int k0 = 0; k0 < K; k0 += 64) {
    __syncthreads();
#pragma unroll
    for (int i = 0; i < 4; ++i) {
      int m = m0 + rr + 16 * i;
      int mc = m < M ? m : M - 1;
      int kk = k0 + cl;
      float4 a = *(const float4*)(Opart + (size_t)mc * 128 + kk);
      float4 c = *(const float4*)(Opart + ((size_t)16384 + mc) * 128 + kk);
      float4 e = *(const float4*)(Opart + ((size_t)32768 + mc) * 128 + kk);
      int rl = rr + 16 * i;
      float w0 = RW[rl][0], w1 = RW[rl][1], w2 = RW[rl][2], inv = RW[rl][3];
      float4 f = make_float4((a.x * w0 + c.x * w1 + e.x * w2) * inv,
                             (a.y * w0 + c.y * w1 + e.y * w2) * inv,
                             (a.z * w0 + c.z * w1 + e.z * w2) * inv,
                             (a.w * w0 + c.w * w1 + e.w * w2) * inv);
      *(uint2*)(As + (size_t)rl * 72 + cl) = cvt4(f);
    }
#pragma unroll
    for (int i = 0; i < 4; ++i) {
      int n = r8 + 32 * i;
      *(bf16x8*)(Ws + (size_t)n * 72 + c8) =
          *(const bf16x8*)(Wb + (size_t)n * K + k0 + c8);
    }
    __syncthreads();
#pragma unroll
    for (int ks = 0; ks < 2; ++ks) {
      bf16x8 af[4], bfr[2];
#pragma unroll
      for (int mf = 0; mf < 4; ++mf)
        af[mf] = *(const bf16x8*)(As + (size_t)(mf * 16 + ln) * 72 + ks * 32 + qd * 8);
#pragma unroll
      for (int nf = 0; nf < 2; ++nf)
        bfr[nf] = *(const bf16x8*)(Ws + (size_t)(w * 32 + nf * 16 + ln) * 72 + ks * 32 + qd * 8);
#pragma unroll
      for (int mf = 0; mf < 4; ++mf)
#pragma unroll
        for (int nf = 0; nf < 2; ++nf)
          acc[mf][nf] = __builtin_amdgcn_mfma_f32_16x16x32_bf16(af[mf], bfr[nf], acc[mf][nf], 0, 0, 0);
    }
  }

  if (HEAD) {
    __syncthreads();
#pragma unroll
    for (int mf = 0; mf < 4; ++mf) {
#pragma unroll
      for (int r = 0; r < 4; ++r) {
        int rowL = mf * 16 + qd * 4 + r;
#pragma unroll
        for (int nf = 0; nf < 2; ++nf) {
          int n = w * 32 + nf * 16 + ln;
          Ct[rowL][n] = acc[mf][nf][r] + bias[n];
        }
      }
    }
    __syncthreads();
    int row = t >> 2, qg = t & 3;
    int m = m0 + row;
    float p = 0.f;
#pragma unroll
    for (int j = 0; j < 32; ++j) {
      int c = qg + j * 4;
      p += Ct[row][c] * bpW[c];
    }
    p += __shfl_xor(p, 1);
    p += __shfl_xor(p, 2);
    if (qg == 0 && m < M)
      out[m] = 1.f / (1.f + __expf(-(p + bpb[0])));
  } else {
#pragma unroll
    for (int mf = 0; mf < 4; ++mf) {
#pragma unroll
      for (int r = 0; r < 4; ++r) {
        int m = m0 + mf * 16 + qd * 4 + r;
        if (m < M) {
#pragma unroll
          for (int nf = 0; nf < 2; ++nf) {
            int n = w * 32 + nf * 16 + ln;
            out[(size_t)m * 128 + n] = acc[mf][nf][r] + bias[n];
          }
        }
      }
    }
  }
}

// ---------------------------------------------------------------------------
// Cumsum over s of e (S,B,128): 64 chunks x 32 rows (512 blocks p1).
// ---------------------------------------------------------------------------
__global__ void cumsum_p1(const float* __restrict__ e, float* __restrict__ csum,
                          float* __restrict__ part)
{
  int chunk = blockIdx.x, b = blockIdx.y, d = threadIdx.x;
  float run = 0.f;
  int s0 = chunk * 32;
  for (int s = 0; s < 32; ++s) {
    size_t idx = ((size_t)(s0 + s) * 8 + b) * 128 + d;
    run += e[idx];
    csum[idx] = run;
  }
  part[(b * 64 + chunk) * 128 + d] = run;
}

__global__ void cumsum_p2(float* __restrict__ part)
{
  int b = blockIdx.x, d = threadIdx.x;
  float run = 0.f;
  for (int c = 0; c < 64; ++c) {
    float v = part[(b * 64 + c) * 128 + d];
    part[(b * 64 + c) * 128 + d] = run;
    run += v;
  }
}

// ---------------------------------------------------------------------------
extern "C" void kernel_launch(void* const* d_in, const int* in_sizes, int n_in,
                              void* d_out, int out_size, void* d_ws, size_t ws_size,
                              hipStream_t stream)
{
  const float* x       = (const float*)d_in[0];
  const float* pW      = (const float*)d_in[1];
  const float* pb      = (const float*)d_in[2];
  const float* cW      = (const float*)d_in[3];
  const float* cb      = (const float*)d_in[4];
  const float* aW      = (const float*)d_in[5];
  const float* ab      = (const float*)d_in[6];
  const float* uW      = (const float*)d_in[7];
  const float* ub      = (const float*)d_in[8];
  const float* eW      = (const float*)d_in[9];
  const float* eb      = (const float*)d_in[10];
  const float* la_win  = (const float*)d_in[11];
  const float* la_bin  = (const float*)d_in[12];
  const float* la_wout = (const float*)d_in[13];
  const float* la_bout = (const float*)d_in[14];
  const float* beW     = (const float*)d_in[15];
  const float* beb     = (const float*)d_in[16];
  const float* ba_win  = (const float*)d_in[17];
  const float* ba_bin  = (const float*)d_in[18];
  const float* ba_wout = (const float*)d_in[19];
  const float* ba_bout = (const float*)d_in[20];
  const float* bpW     = (const float*)d_in[21];
  const float* bpb     = (const float*)d_in[22];

  float* ws   = (float*)d_ws;
  float* outF = (float*)d_out;

  uint16_t* WB  = (uint16_t*)ws;
  float* base   = ws + 344064;
  uint16_t* featsB = (uint16_t*)base;
  float* csumB  = base;
  float* partB  = base + 2097152;
  uint16_t* eB  = (uint16_t*)(base + 4194304);   // e0 / b0
  uint16_t* projB = (uint16_t*)(base + 5242880);
  uint16_t* VtbB  = (uint16_t*)(base + 8388608);
  float* OpartB = base + 9437184;
  float* mlB    = base + 15728640;

  // 0. weights -> bf16
  WPtrs wp;
  wp.p[0] = pW; wp.p[1] = cW; wp.p[2] = aW; wp.p[3] = uW; wp.p[4] = eW;
  wp.p[5] = la_win; wp.p[6] = la_wout; wp.p[7] = beW; wp.p[8] = ba_win; wp.p[9] = ba_wout;
  pack_weights<<<dim3(672), 256, 0, stream>>>(wp, WB);

  // 1. feats = relu(segment linears) -> bf16
  gemm_feats64<<<dim3(256, 4), 256, 0, stream>>>(x, WB, pb, cb, ab, ub, featsB);
  // 2. e0 = relu(feats @ eW^T + eb) -> bf16, remapped (B,S)->(S,B)
  gemm64<true, true, true, true><<<dim3(256, 1), 256, 0, stream>>>(
      featsB, 512, WB + OFF_EW, eb, eB, 128, 16384, 512);
  // 3. proj1 = e0 @ la_win^T + la_bin -> bf16
  gemm64<true, true, false, false><<<dim3(256, 3), 256, 0, stream>>>(
      eB, 128, WB + OFF_LAWIN, la_bin, projB, 384, 16384, 128);
  // 4. V pack + 3-split flash
  vpack<<<dim3(32, 8), 256, 0, stream>>>(projB, VtbB, 2048);
  attn_split3<<<dim3(32, 8, 3), 256, 0, stream>>>(projB, VtbB, OpartB, mlB, 2048);
  // 5. e = combine(att1) @ la_wout^T + la_bout -> d_out (fp32), combine inlined
  gemm_attc64<false><<<dim3(256), 256, 0, stream>>>(
      OpartB, mlB, WB + OFF_LAWOUT, la_bout, nullptr, nullptr, outF, 16384);
  // 6-7. csum (local prefixes + chunk offsets; p3 fused into becat)
  cumsum_p1<<<dim3(64, 8), 128, 0, stream>>>(outF, csumB, partB);
  cumsum_p2<<<dim3(8), 128, 0, stream>>>(partB);
  // 8. b0 = relu(cat(left,right) @ beW^T + beb) -> bf16
  gemm_becat64<<<dim3(256), 256, 0, stream>>>(csumB, partB, WB + OFF_BEW, beb, eB);
  // 9. proj2
  gemm64<true, true, false, false><<<dim3(256, 3), 256, 0, stream>>>(
      eB, 128, WB + OFF_BAWIN, ba_bin, projB, 384, 16376, 128);
  // 10. V pack + att2 (Slen = 2047)
  vpack<<<dim3(32, 8), 256, 0, stream>>>(projB, VtbB, 2047);
  attn_split3<<<dim3(32, 8, 3), 256, 0, stream>>>(projB, VtbB, OpartB, mlB, 2047);
  // 11. bout GEMM: combine inlined + fused sigmoid head -> d_out tail
  gemm_attc64<true><<<dim3(256), 256, 0, stream>>>(
      OpartB, mlB, WB + OFF_BAWOUT, ba_bout, bpW, bpb, outF + 2097152, 16376);
}

// Round 6
// 517.075 us; speedup vs baseline: 1.3066x; 1.0043x over previous
//
#include <hip/hip_runtime.h>
#include <hip/hip_bf16.h>
#include <math.h>
#include <stdint.h>

// ---------------------------------------------------------------------------
// SceneSegmenter Round 10: raw-barrier async round.
//  - gemm64 / gemm_feats64 / gemm_attc64 / attn_split3 k-loops use raw
//    s_barrier + counted waitcnt (m201 pattern): vmcnt(0); LDS-write;
//    lgkmcnt(0); barrier; issue k+1 loads; compute; barrier.
//    __syncthreads' vmcnt(0) drain no longer kills the prefetch.
//  - attn: s_setprio(1) around MFMA clusters (T5).
//  - becat/vpack/cumsum/pack unchanged (old structure).
// Layouts: token-major activations (S, B, D) flat, row = s*8+b.
// ---------------------------------------------------------------------------

#define DEV static __device__ __forceinline__

typedef __attribute__((ext_vector_type(8))) short bf16x8;   // 8 bf16 (4 VGPRs)
typedef __attribute__((ext_vector_type(4))) float f32x4;    // MFMA C/D

DEV uint32_t pk2bf(float a, float b) {       // packed fp32x2 -> bf16x2 (RNE)
  __hip_bfloat162 h = __float22bfloat162_rn(make_float2(a, b));
  return *(uint32_t*)&h;
}
DEV uint2 cvt4(float4 f) {                   // 4 fp32 -> 4 bf16
  return make_uint2(pk2bf(f.x, f.y), pk2bf(f.z, f.w));
}
DEV uint16_t bf1(float a) { return (uint16_t)(pk2bf(a, 0.f) & 0xffffu); }
DEV float frombf(uint16_t h) {
  union { uint32_t u; float f; } v; v.u = ((uint32_t)h) << 16; return v.f;
}

#define WAIT_VM0()  __asm__ volatile("s_waitcnt vmcnt(0)" ::: "memory")
#define WAIT_LGKM0() __asm__ volatile("s_waitcnt lgkmcnt(0)" ::: "memory")
#define RAW_BARRIER() __builtin_amdgcn_s_barrier()

// Weight-pack offsets (halves) inside WB
#define OFF_PW      0u
#define OFF_CW      262144u
#define OFF_AW      327680u
#define OFF_UW      393216u
#define OFF_EW      458752u
#define OFF_LAWIN   524288u
#define OFF_LAWOUT  573440u
#define OFF_BEW     589824u
#define OFF_BAWIN   622592u
#define OFF_BAWOUT  671744u
#define OFF_END     688128u

struct WPtrs { const float* p[10]; };

// ---------------------------------------------------------------------------
// pack_weights: concatenated fp32 weights -> bf16 WB. 672 blocks x 256 thr.
// ---------------------------------------------------------------------------
__global__ __launch_bounds__(256) void pack_weights(WPtrs wp, uint16_t* __restrict__ WB)
{
  const uint32_t off[11] = {OFF_PW, OFF_CW, OFF_AW, OFF_UW, OFF_EW, OFF_LAWIN,
                            OFF_LAWOUT, OFF_BEW, OFF_BAWIN, OFF_BAWOUT, OFF_END};
  uint32_t h = (blockIdx.x * 256u + threadIdx.x) * 4u;
  if (h >= OFF_END) return;
  int s = 0;
  while (h >= off[s + 1]) ++s;
  float4 f = *(const float4*)(wp.p[s] + (h - off[s]));
  *(uint2*)(WB + h) = cvt4(f);
}

// ---------------------------------------------------------------------------
// Templated bf16 MFMA GEMM, BM=64 x BN=128, BK=64, 256 thr = 4 waves.
// Raw-barrier async k-loop: loads for step k+1 fly under compute of step k.
// ---------------------------------------------------------------------------
template<bool ABF, bool OBF, bool RELU, bool REMAP>
__global__ __launch_bounds__(256) void gemm64(
    const void* __restrict__ Ap, int lda,
    const uint16_t* __restrict__ Wb,
    const float* __restrict__ bias,
    void* __restrict__ Cp, int ldc,
    int M, int K)
{
  __shared__ __align__(16) uint16_t As[64 * 72];
  __shared__ __align__(16) uint16_t Ws[128 * 72];

  const int t  = threadIdx.x;
  const int m0 = blockIdx.x * 64;
  const int n0 = blockIdx.y * 128;
  const int w  = t >> 6, l = t & 63;
  const int ln = l & 15, qd = l >> 4;

  f32x4 acc[4][2];
#pragma unroll
  for (int i = 0; i < 4; ++i) { acc[i][0] = (f32x4){0,0,0,0}; acc[i][1] = (f32x4){0,0,0,0}; }

  const int rr = t >> 4;          // fp32-A path: 16 rows
  const int cl = (t & 15) * 4;
  const int r8 = t >> 3;          // bf16 paths: 32 rows
  const int c8 = (t & 7) * 8;     // half col (16B)

  float4 a32[4];
  bf16x8 a16[2];
  bf16x8 wreg[4];

  auto loadA = [&](int k0) {
    if (ABF) {
      const uint16_t* A = (const uint16_t*)Ap;
#pragma unroll
      for (int i = 0; i < 2; ++i) {
        int m = m0 + r8 + 32 * i;
        int mc = m < M ? m : M - 1;
        a16[i] = *(const bf16x8*)(A + (size_t)mc * lda + k0 + c8);
      }
    } else {
      const float* A = (const float*)Ap;
#pragma unroll
      for (int i = 0; i < 4; ++i) {
        int m = m0 + rr + 16 * i;
        int mc = m < M ? m : M - 1;
        a32[i] = *(const float4*)(A + (size_t)mc * lda + k0 + cl);
      }
    }
#pragma unroll
    for (int i = 0; i < 4; ++i) {
      int n = r8 + 32 * i;
      wreg[i] = *(const bf16x8*)(Wb + (size_t)(n0 + n) * K + k0 + c8);
    }
  };
  auto writeLDS = [&]() {
    if (ABF) {
#pragma unroll
      for (int i = 0; i < 2; ++i)
        *(bf16x8*)(As + (size_t)(r8 + 32 * i) * 72 + c8) = a16[i];
    } else {
#pragma unroll
      for (int i = 0; i < 4; ++i)
        *(uint2*)(As + (size_t)(rr + 16 * i) * 72 + cl) = cvt4(a32[i]);
    }
#pragma unroll
    for (int i = 0; i < 4; ++i)
      *(bf16x8*)(Ws + (size_t)(r8 + 32 * i) * 72 + c8) = wreg[i];
  };

  loadA(0);
  for (int k0 = 0; k0 < K; k0 += 64) {
    WAIT_VM0();                 // step-k regs arrived
    writeLDS();
    WAIT_LGKM0();               // my LDS writes done
    RAW_BARRIER();              // all waves' writes visible
    if (k0 + 64 < K) loadA(k0 + 64);   // in flight under compute
#pragma unroll
    for (int ks = 0; ks < 2; ++ks) {
      bf16x8 af[4], bfr[2];
#pragma unroll
      for (int mf = 0; mf < 4; ++mf)
        af[mf] = *(const bf16x8*)(As + (size_t)(mf * 16 + ln) * 72 + ks * 32 + qd * 8);
#pragma unroll
      for (int nf = 0; nf < 2; ++nf)
        bfr[nf] = *(const bf16x8*)(Ws + (size_t)(w * 32 + nf * 16 + ln) * 72 + ks * 32 + qd * 8);
#pragma unroll
      for (int mf = 0; mf < 4; ++mf)
#pragma unroll
        for (int nf = 0; nf < 2; ++nf)
          acc[mf][nf] = __builtin_amdgcn_mfma_f32_16x16x32_bf16(af[mf], bfr[nf], acc[mf][nf], 0, 0, 0);
    }
    RAW_BARRIER();              // all waves done reading LDS
  }

#pragma unroll
  for (int mf = 0; mf < 4; ++mf) {
#pragma unroll
    for (int r = 0; r < 4; ++r) {
      int m = m0 + mf * 16 + qd * 4 + r;
      if (m < M) {
        size_t ro = REMAP ? (size_t)((m & 2047) * 8 + (m >> 11)) : (size_t)m;
#pragma unroll
        for (int nf = 0; nf < 2; ++nf) {
          int n = n0 + w * 32 + nf * 16 + ln;
          float v = acc[mf][nf][r] + bias[n];
          if (RELU) v = fmaxf(v, 0.f);
          if (OBF) ((uint16_t*)Cp)[ro * (size_t)ldc + n] = bf1(v);
          else     ((float*)Cp)[ro * (size_t)ldc + n] = v;
        }
      }
    }
  }
}

// ---------------------------------------------------------------------------
// Fused 4-segment feats GEMM (A = x fp32, W bf16), raw-barrier async k-loop.
// ---------------------------------------------------------------------------
__global__ __launch_bounds__(256) void gemm_feats64(
    const float* __restrict__ x, const uint16_t* __restrict__ WB,
    const float* __restrict__ pb, const float* __restrict__ cb,
    const float* __restrict__ ab, const float* __restrict__ ub,
    uint16_t* __restrict__ feats)
{
  __shared__ __align__(16) uint16_t As[64 * 72];
  __shared__ __align__(16) uint16_t Ws[128 * 72];

  const int seg = blockIdx.y;
  const uint16_t* Wb; const float* bias; int kbase, Kseg;
  if (seg == 0)      { Wb = WB + OFF_PW; bias = pb; kbase = 0;    Kseg = 2048; }
  else if (seg == 1) { Wb = WB + OFF_CW; bias = cb; kbase = 2048; Kseg = 512; }
  else if (seg == 2) { Wb = WB + OFF_AW; bias = ab; kbase = 2560; Kseg = 512; }
  else               { Wb = WB + OFF_UW; bias = ub; kbase = 3072; Kseg = 512; }

  const int t  = threadIdx.x;
  const int m0 = blockIdx.x * 64;
  const int w  = t >> 6, l = t & 63;
  const int ln = l & 15, qd = l >> 4;

  f32x4 acc[4][2];
#pragma unroll
  for (int i = 0; i < 4; ++i) { acc[i][0] = (f32x4){0,0,0,0}; acc[i][1] = (f32x4){0,0,0,0}; }

  const int rr = t >> 4;
  const int cl = (t & 15) * 4;
  const int r8 = t >> 3;
  const int c8 = (t & 7) * 8;

  float4 a32[4];
  bf16x8 wreg[4];

  auto loadA = [&](int k0) {
#pragma unroll
    for (int i = 0; i < 4; ++i) {
      int m = m0 + rr + 16 * i;
      a32[i] = *(const float4*)(x + (size_t)m * 3584 + kbase + k0 + cl);
    }
#pragma unroll
    for (int i = 0; i < 4; ++i) {
      int n = r8 + 32 * i;
      wreg[i] = *(const bf16x8*)(Wb + (size_t)n * Kseg + k0 + c8);
    }
  };

  loadA(0);
  for (int k0 = 0; k0 < Kseg; k0 += 64) {
    WAIT_VM0();
#pragma unroll
    for (int i = 0; i < 4; ++i)
      *(uint2*)(As + (size_t)(rr + 16 * i) * 72 + cl) = cvt4(a32[i]);
#pragma unroll
    for (int i = 0; i < 4; ++i)
      *(bf16x8*)(Ws + (size_t)(r8 + 32 * i) * 72 + c8) = wreg[i];
    WAIT_LGKM0();
    RAW_BARRIER();
    if (k0 + 64 < Kseg) loadA(k0 + 64);
#pragma unroll
    for (int ks = 0; ks < 2; ++ks) {
      bf16x8 af[4], bfr[2];
#pragma unroll
      for (int mf = 0; mf < 4; ++mf)
        af[mf] = *(const bf16x8*)(As + (size_t)(mf * 16 + ln) * 72 + ks * 32 + qd * 8);
#pragma unroll
      for (int nf = 0; nf < 2; ++nf)
        bfr[nf] = *(const bf16x8*)(Ws + (size_t)(w * 32 + nf * 16 + ln) * 72 + ks * 32 + qd * 8);
#pragma unroll
      for (int mf = 0; mf < 4; ++mf)
#pragma unroll
        for (int nf = 0; nf < 2; ++nf)
          acc[mf][nf] = __builtin_amdgcn_mfma_f32_16x16x32_bf16(af[mf], bfr[nf], acc[mf][nf], 0, 0, 0);
    }
    RAW_BARRIER();
  }

#pragma unroll
  for (int mf = 0; mf < 4; ++mf) {
#pragma unroll
    for (int r = 0; r < 4; ++r) {
      int m = m0 + mf * 16 + qd * 4 + r;
#pragma unroll
      for (int nf = 0; nf < 2; ++nf) {
        int n = w * 32 + nf * 16 + ln;
        float v = fmaxf(acc[mf][nf][r] + bias[n], 0.f);
        feats[(size_t)m * 512 + seg * 128 + n] = bf1(v);
      }
    }
  }
}

// ---------------------------------------------------------------------------
// becat GEMM with fused cumsum chunk-offset (p3) — unchanged structure.
// ---------------------------------------------------------------------------
__global__ __launch_bounds__(256) void gemm_becat64(
    const float* __restrict__ csum, const float* __restrict__ part,
    const uint16_t* __restrict__ Wb, const float* __restrict__ bias,
    uint16_t* __restrict__ C)
{
  __shared__ __align__(16) uint16_t As[64 * 72];
  __shared__ __align__(16) uint16_t Ws[128 * 72];

  const int M = 16376, K = 256;
  const int t  = threadIdx.x;
  const int m0 = blockIdx.x * 64;
  const int w  = t >> 6, l = t & 63;
  const int ln = l & 15, qd = l >> 4;

  f32x4 acc[4][2];
#pragma unroll
  for (int i = 0; i < 4; ++i) { acc[i][0] = (f32x4){0,0,0,0}; acc[i][1] = (f32x4){0,0,0,0}; }

  const int rr = t >> 4;
  const int cl = (t & 15) * 4;
  const int r8 = t >> 3;
  const int c8 = (t & 7) * 8;

  for (int k0 = 0; k0 < K; k0 += 64) {
    __syncthreads();
#pragma unroll
    for (int i = 0; i < 4; ++i) {
      int m = m0 + rr + 16 * i;
      int mc = m < M ? m : M - 1;
      int j = mc >> 3, bb = mc & 7;
      int kk = k0 + cl;
      float4 f;
      if (kk < 128) {
        float4 v = *(const float4*)(csum + (size_t)mc * 128 + kk);
        float4 p = *(const float4*)(part + (size_t)(bb * 64 + (j >> 5)) * 128 + kk);
        float s = 1.f / (float)(j + 1);
        f = make_float4((v.x + p.x) * s, (v.y + p.y) * s,
                        (v.z + p.z) * s, (v.w + p.w) * s);
      } else {
        int d = kk - 128;
        float4 c0 = *(const float4*)(csum + (size_t)mc * 128 + d);
        float4 p0 = *(const float4*)(part + (size_t)(bb * 64 + (j >> 5)) * 128 + d);
        float4 ct = *(const float4*)(csum + (size_t)(16376 + bb) * 128 + d);
        float4 pt = *(const float4*)(part + (size_t)(bb * 64 + 63) * 128 + d);
        float s = 1.f / (float)(2047 - j);
        f = make_float4(((ct.x + pt.x) - (c0.x + p0.x)) * s,
                        ((ct.y + pt.y) - (c0.y + p0.y)) * s,
                        ((ct.z + pt.z) - (c0.z + p0.z)) * s,
                        ((ct.w + pt.w) - (c0.w + p0.w)) * s);
      }
      *(uint2*)(As + (size_t)(rr + 16 * i) * 72 + cl) = cvt4(f);
    }
#pragma unroll
    for (int i = 0; i < 4; ++i) {
      int n = r8 + 32 * i;
      *(bf16x8*)(Ws + (size_t)n * 72 + c8) =
          *(const bf16x8*)(Wb + (size_t)n * K + k0 + c8);
    }
    __syncthreads();
#pragma unroll
    for (int ks = 0; ks < 2; ++ks) {
      bf16x8 af[4], bfr[2];
#pragma unroll
      for (int mf = 0; mf < 4; ++mf)
        af[mf] = *(const bf16x8*)(As + (size_t)(mf * 16 + ln) * 72 + ks * 32 + qd * 8);
#pragma unroll
      for (int nf = 0; nf < 2; ++nf)
        bfr[nf] = *(const bf16x8*)(Ws + (size_t)(w * 32 + nf * 16 + ln) * 72 + ks * 32 + qd * 8);
#pragma unroll
      for (int mf = 0; mf < 4; ++mf)
#pragma unroll
        for (int nf = 0; nf < 2; ++nf)
          acc[mf][nf] = __builtin_amdgcn_mfma_f32_16x16x32_bf16(af[mf], bfr[nf], acc[mf][nf], 0, 0, 0);
    }
  }

#pragma unroll
  for (int mf = 0; mf < 4; ++mf) {
#pragma unroll
    for (int r = 0; r < 4; ++r) {
      int m = m0 + mf * 16 + qd * 4 + r;
      if (m < M) {
#pragma unroll
        for (int nf = 0; nf < 2; ++nf) {
          int n = w * 32 + nf * 16 + ln;
          C[(size_t)m * 128 + n] = bf1(fmaxf(acc[mf][nf][r] + bias[n], 0.f));
        }
      }
    }
  }
}

// ---------------------------------------------------------------------------
// vpack: V third of bf16 proj -> Vtb [b][tile32][d128][key64].
// u32 slot u holds keys K,K+1, K = 32(u>>4)+16((u>>1)&1)+4((u>>2)&3)+2(u&1).
// ---------------------------------------------------------------------------
__global__ __launch_bounds__(256) void vpack(
    const uint16_t* __restrict__ proj, uint16_t* __restrict__ Vtb, int Slen)
{
  __shared__ __align__(16) uint16_t Vs[64][136];

  const int kt = blockIdx.x, b = blockIdx.y, t = threadIdx.x;
  const int sl = t >> 2, cg = (t & 3) * 32;
  const int s  = kt * 64 + sl;
  const int valid = s < Slen;
  const int sc2 = valid ? s : Slen - 1;
  const uint16_t* src = proj + ((size_t)sc2 * 8 + b) * 384 + 256 + cg;
#pragma unroll
  for (int i = 0; i < 4; ++i) {
    bf16x8 v;
    if (valid) v = *(const bf16x8*)(src + i * 8);
    else       v = (bf16x8){0,0,0,0,0,0,0,0};
    *(bf16x8*)(&Vs[sl][cg + i * 8]) = v;
  }
  __syncthreads();
  const int d = t >> 1, hh = t & 1;     // hh = ks2 half (keys 32hh..32hh+31)
  uint32_t wv[16];
#pragma unroll
  for (int i = 0; i < 16; ++i) {
    int K = 32 * hh + 16 * ((i >> 1) & 1) + 4 * ((i >> 2) & 3) + 2 * (i & 1);
    wv[i] = (uint32_t)Vs[K][d] | ((uint32_t)Vs[K + 1][d] << 16);
  }
  uint16_t* dv = Vtb + (((size_t)b * 32 + kt) * 128 + d) * 64 + hh * 32;
#pragma unroll
  for (int i = 0; i < 4; ++i)
    *(uint4*)(dv + i * 8) = *(uint4*)(&wv[i * 4]);
}

// ---------------------------------------------------------------------------
// 3-way split-K flash attention, swapped QK^T + raw-barrier async staging +
// setprio around MFMA clusters.
// ---------------------------------------------------------------------------
__global__ __launch_bounds__(256, 3) void attn_split3(
    const uint16_t* __restrict__ proj, const uint16_t* __restrict__ Vtb,
    float* __restrict__ Opart, float* __restrict__ ml, int Slen)
{
  __shared__ __align__(16) uint16_t KsL[64 * 136];     // [key][k], pitch 136
  __shared__ __align__(16) uint16_t VtL[128 * 72];     // [d][k'],  pitch 72

  const int t  = threadIdx.x;
  const int b  = blockIdx.y;
  const int q0 = blockIdx.x * 64;
  const int split = blockIdx.z;
  const int kbeg = split * 704;
  const int kend = (split == 2) ? Slen : kbeg + 704;
  const int w  = t >> 6;
  const int l  = t & 63;
  const int ln = l & 15;
  const int qd = l >> 4;
  const float scl = 0.08838834764831845f;   // 1/sqrt(128)

  const int kkey = t >> 2, kcg = (t & 3) * 32;   // K staging map
  const int vd   = t >> 1, vh  = (t & 1) * 32;   // V staging map

  bf16x8 qf[4];
  {
    int qrow = q0 + w * 16 + ln;
    int qc = qrow < Slen ? qrow : Slen - 1;
    const uint16_t* qp = proj + ((size_t)qc * 8 + b) * 384 + qd * 8;
#pragma unroll
    for (int ks = 0; ks < 4; ++ks) {
      union { bf16x8 v; uint16_t h[8]; uint32_t u[4]; } in, out;
      in.v = *(const bf16x8*)(qp + ks * 32);
#pragma unroll
      for (int j = 0; j < 4; ++j)
        out.u[j] = pk2bf(frombf(in.h[2 * j]) * scl, frombf(in.h[2 * j + 1]) * scl);
      qf[ks] = out.v;
    }
  }

  f32x4 oacc[8];
#pragma unroll
  for (int i = 0; i < 8; ++i) oacc[i] = (f32x4){0.f, 0.f, 0.f, 0.f};
  float mrow = -INFINITY;          // per-lane: q = q0 + w*16 + ln
  float lrow = 0.f;

  const int ntiles = (kend - kbeg + 63) >> 6;

  bf16x8 kreg[4], vreg[4];
  auto loadTile = [&](int kt) {
    int kg = kbeg + kt * 64 + kkey;
    int kc = kg < Slen ? kg : Slen - 1;
    const uint16_t* ksrc = proj + ((size_t)kc * 8 + b) * 384 + 128 + kcg;
#pragma unroll
    for (int i = 0; i < 4; ++i) kreg[i] = *(const bf16x8*)(ksrc + i * 8);
    const int tile = 11 * split + kt;
    const uint16_t* vsrc = Vtb + (((size_t)b * 32 + tile) * 128 + vd) * 64 + vh;
#pragma unroll
    for (int i = 0; i < 4; ++i) vreg[i] = *(const bf16x8*)(vsrc + i * 8);
  };

  loadTile(0);
  for (int kt = 0; kt < ntiles; ++kt) {
    WAIT_VM0();                          // staged regs arrived
    {
      uint16_t* kdst = KsL + kkey * 136 + kcg;
#pragma unroll
      for (int i = 0; i < 4; ++i) *(bf16x8*)(kdst + i * 8) = kreg[i];
      uint16_t* vdst = VtL + vd * 72 + vh;
#pragma unroll
      for (int i = 0; i < 4; ++i) *(bf16x8*)(vdst + i * 8) = vreg[i];
    }
    WAIT_LGKM0();
    RAW_BARRIER();                       // LDS ready for all waves
    if (kt + 1 < ntiles) loadTile(kt + 1);   // in flight under compute

    // QK^T swapped: lane holds S[key = nf*16 + qd*4 + r][q = ln]
    float sc[4][4];
    __builtin_amdgcn_s_setprio(1);
#pragma unroll
    for (int nf = 0; nf < 4; ++nf) {
      f32x4 acc = (f32x4){0.f, 0.f, 0.f, 0.f};
#pragma unroll
      for (int ks = 0; ks < 4; ++ks) {
        bf16x8 kf = *(const bf16x8*)(KsL + (size_t)(nf * 16 + ln) * 136 + ks * 32 + qd * 8);
        acc = __builtin_amdgcn_mfma_f32_16x16x32_bf16(kf, qf[ks], acc, 0, 0, 0);
      }
      int keyb = kbeg + kt * 64 + nf * 16 + qd * 4;
#pragma unroll
      for (int r = 0; r < 4; ++r)
        sc[nf][r] = (keyb + r < kend) ? acc[r] : -1e30f;
    }
    __builtin_amdgcn_s_setprio(0);

    // online softmax: in-lane 16-max + 2 shuffles
    float mx = sc[0][0];
#pragma unroll
    for (int nf = 0; nf < 4; ++nf)
#pragma unroll
      for (int r = 0; r < 4; ++r) mx = fmaxf(mx, sc[nf][r]);
    mx = fmaxf(mx, __shfl_xor(mx, 16));
    mx = fmaxf(mx, __shfl_xor(mx, 32));
    float mNew = fmaxf(mrow, mx);

    float ps = 0.f;
#pragma unroll
    for (int nf = 0; nf < 4; ++nf) {
      float p0 = __expf(sc[nf][0] - mNew);
      float p1 = __expf(sc[nf][1] - mNew);
      float p2 = __expf(sc[nf][2] - mNew);
      float p3 = __expf(sc[nf][3] - mNew);
      sc[nf][0] = p0; sc[nf][1] = p1; sc[nf][2] = p2; sc[nf][3] = p3;
      ps += (p0 + p1) + (p2 + p3);
    }
    ps += __shfl_xor(ps, 16);
    ps += __shfl_xor(ps, 32);

    float alpha = __expf(mrow - mNew);
    mrow = mNew;
    lrow = lrow * alpha + ps;

    // alpha for the lane's OUTPUT rows q' = qd*4 + r
    float alphaR[4];
#pragma unroll
    for (int r = 0; r < 4; ++r)
      alphaR[r] = __shfl(alpha, (l & 48) | (qd * 4 + r));
#pragma unroll
    for (int no = 0; no < 8; ++no) {
#pragma unroll
      for (int r = 0; r < 4; ++r) oacc[no][r] *= alphaR[r];
    }

    // in-register P -> PV A-fragments (order matches vpack permutation)
    union { bf16x8 v; uint32_t u[4]; } pa0, pa1;
#pragma unroll
    for (int i = 0; i < 4; ++i) {
      pa0.u[i] = pk2bf(sc[(i >> 1)][(i & 1) * 2],     sc[(i >> 1)][(i & 1) * 2 + 1]);
      pa1.u[i] = pk2bf(sc[2 + (i >> 1)][(i & 1) * 2], sc[2 + (i >> 1)][(i & 1) * 2 + 1]);
    }
    __builtin_amdgcn_s_setprio(1);
#pragma unroll
    for (int no = 0; no < 8; ++no) {
      bf16x8 vf = *(const bf16x8*)(VtL + (size_t)(no * 16 + ln) * 72 + qd * 8);
      oacc[no] = __builtin_amdgcn_mfma_f32_16x16x32_bf16(pa0.v, vf, oacc[no], 0, 0, 0);
    }
#pragma unroll
    for (int no = 0; no < 8; ++no) {
      bf16x8 vf = *(const bf16x8*)(VtL + (size_t)(no * 16 + ln) * 72 + 32 + qd * 8);
      oacc[no] = __builtin_amdgcn_mfma_f32_16x16x32_bf16(pa1.v, vf, oacc[no], 0, 0, 0);
    }
    __builtin_amdgcn_s_setprio(0);
    RAW_BARRIER();                       // all waves done reading LDS
  }

  // store unnormalized partials + (m, l)
#pragma unroll
  for (int r = 0; r < 4; ++r) {
    int qg = q0 + w * 16 + qd * 4 + r;
    if (qg < Slen) {
      size_t row = (size_t)qg * 8 + b;
      float* dst = Opart + ((size_t)split * 16384 + row) * 128 + ln;
#pragma unroll
      for (int no = 0; no < 8; ++no) dst[no * 16] = oacc[no][r];
    }
  }
  {
    int qg = q0 + w * 16 + ln;
    if (qd == 0 && qg < Slen) {
      size_t row = (size_t)qg * 8 + b;
      ml[((size_t)split * 16384 + row) * 2 + 0] = mrow;
      ml[((size_t)split * 16384 + row) * 2 + 1] = lrow;
    }
  }
}

// ---------------------------------------------------------------------------
// Out-proj GEMM with INLINE split-combine A-staging, raw-barrier async.
// ---------------------------------------------------------------------------
template<bool HEAD>
__global__ __launch_bounds__(256) void gemm_attc64(
    const float* __restrict__ Opart, const float* __restrict__ ml,
    const uint16_t* __restrict__ Wb,
    const float* __restrict__ bias,
    const float* __restrict__ bpW, const float* __restrict__ bpb,
    float* __restrict__ out, int M)
{
  __shared__ __align__(16) uint16_t As[64 * 72];
  __shared__ __align__(16) uint16_t Ws[128 * 72];
  __shared__ float RW[64][4];                 // w0,w1,w2,inv per row
  __shared__ float Ct[HEAD ? 64 : 1][133];

  const int K = 128;
  const int t  = threadIdx.x;
  const int m0 = blockIdx.x * 64;
  const int w  = t >> 6, l = t & 63;
  const int ln = l & 15, qd = l >> 4;

  if (t < 64) {
    int m = m0 + t;
    int mc = m < M ? m : M - 1;
    float m0v = ml[(size_t)mc * 2],                 l0 = ml[(size_t)mc * 2 + 1];
    float m1v = ml[((size_t)16384 + mc) * 2],       l1 = ml[((size_t)16384 + mc) * 2 + 1];
    float m2v = ml[((size_t)32768 + mc) * 2],       l2 = ml[((size_t)32768 + mc) * 2 + 1];
    float Mx = fmaxf(fmaxf(m0v, m1v), m2v);
    float w0 = __expf(m0v - Mx), w1 = __expf(m1v - Mx), w2 = __expf(m2v - Mx);
    RW[t][0] = w0; RW[t][1] = w1; RW[t][2] = w2;
    RW[t][3] = 1.f / (l0 * w0 + l1 * w1 + l2 * w2);
  }
  __syncthreads();      // RW visible before first (pre-barrier) A-staging

  f32x4 acc[4][2];
#pragma unroll
  for (int i = 0; i < 4; ++i) { acc[i][0] = (f32x4){0,0,0,0}; acc[i][1] = (f32x4){0,0,0,0}; }

  const int rr = t >> 4;
  const int cl = (t & 15) * 4;
  const int r8 = t >> 3;
  const int c8 = (t & 7) * 8;

  float4 ra[4], rc[4], re[4];
  bf16x8 wreg[4];

  auto loadA = [&](int k0) {
#pragma unroll
    for (int i = 0; i < 4; ++i) {
      int m = m0 + rr + 16 * i;
      int mc = m < M ? m : M - 1;
      int kk = k0 + cl;
      ra[i] = *(const float4*)(Opart + (size_t)mc * 128 + kk);
      rc[i] = *(const float4*)(Opart + ((size_t)16384 + mc) * 128 + kk);
      re[i] = *(const float4*)(Opart + ((size_t)32768 + mc) * 128 + kk);
    }
#pragma unroll
    for (int i = 0; i < 4; ++i) {
      int n = r8 + 32 * i;
      wreg[i] = *(const bf16x8*)(Wb + (size_t)n * K + k0 + c8);
    }
  };

  loadA(0);
  for (int k0 = 0; k0 < K; k0 += 64) {
    WAIT_VM0();
#pragma unroll
    for (int i = 0; i < 4; ++i) {
      int rl = rr + 16 * i;
      float w0 = RW[rl][0], w1 = RW[rl][1], w2 = RW[rl][2], inv = RW[rl][3];
      float4 f = make_float4((ra[i].x * w0 + rc[i].x * w1 + re[i].x * w2) * inv,
                             (ra[i].y * w0 + rc[i].y * w1 + re[i].y * w2) * inv,
                             (ra[i].z * w0 + rc[i].z * w1 + re[i].z * w2) * inv,
                             (ra[i].w * w0 + rc[i].w * w1 + re[i].w * w2) * inv);
      *(uint2*)(As + (size_t)rl * 72 + cl) = cvt4(f);
    }
#pragma unroll
    for (int i = 0; i < 4; ++i)
      *(bf16x8*)(Ws + (size_t)(r8 + 32 * i) * 72 + c8) = wreg[i];
    WAIT_LGKM0();
    RAW_BARRIER();
    if (k0 + 64 < K) loadA(k0 + 64);
#pragma unroll
    for (int ks = 0; ks < 2; ++ks) {
      bf16x8 af[4], bfr[2];
#pragma unroll
      for (int mf = 0; mf < 4; ++mf)
        af[mf] = *(const bf16x8*)(As + (size_t)(mf * 16 + ln) * 72 + ks * 32 + qd * 8);
#pragma unroll
      for (int nf = 0; nf < 2; ++nf)
        bfr[nf] = *(const bf16x8*)(Ws + (size_t)(w * 32 + nf * 16 + ln) * 72 + ks * 32 + qd * 8);
#pragma unroll
      for (int mf = 0; mf < 4; ++mf)
#pragma unroll
        for (int nf = 0; nf < 2; ++nf)
          acc[mf][nf] = __builtin_amdgcn_mfma_f32_16x16x32_bf16(af[mf], bfr[nf], acc[mf][nf], 0, 0, 0);
    }
    RAW_BARRIER();
  }

  if (HEAD) {
    __syncthreads();
#pragma unroll
    for (int mf = 0; mf < 4; ++mf) {
#pragma unroll
      for (int r = 0; r < 4; ++r) {
        int rowL = mf * 16 + qd * 4 + r;
#pragma unroll
        for (int nf = 0; nf < 2; ++nf) {
          int n = w * 32 + nf * 16 + ln;
          Ct[rowL][n] = acc[mf][nf][r] + bias[n];
        }
      }
    }
    __syncthreads();
    int row = t >> 2, qg = t & 3;
    int m = m0 + row;
    float p = 0.f;
#pragma unroll
    for (int j = 0; j < 32; ++j) {
      int c = qg + j * 4;
      p += Ct[row][c] * bpW[c];
    }
    p += __shfl_xor(p, 1);
    p += __shfl_xor(p, 2);
    if (qg == 0 && m < M)
      out[m] = 1.f / (1.f + __expf(-(p + bpb[0])));
  } else {
#pragma unroll
    for (int mf = 0; mf < 4; ++mf) {
#pragma unroll
      for (int r = 0; r < 4; ++r) {
        int m = m0 + mf * 16 + qd * 4 + r;
        if (m < M) {
#pragma unroll
          for (int nf = 0; nf < 2; ++nf) {
            int n = w * 32 + nf * 16 + ln;
            out[(size_t)m * 128 + n] = acc[mf][nf][r] + bias[n];
          }
        }
      }
    }
  }
}

// ---------------------------------------------------------------------------
// Cumsum over s of e (S,B,128): 64 chunks x 32 rows (512 blocks p1).
// ---------------------------------------------------------------------------
__global__ void cumsum_p1(const float* __restrict__ e, float* __restrict__ csum,
                          float* __restrict__ part)
{
  int chunk = blockIdx.x, b = blockIdx.y, d = threadIdx.x;
  float run = 0.f;
  int s0 = chunk * 32;
  for (int s = 0; s < 32; ++s) {
    size_t idx = ((size_t)(s0 + s) * 8 + b) * 128 + d;
    run += e[idx];
    csum[idx] = run;
  }
  part[(b * 64 + chunk) * 128 + d] = run;
}

__global__ void cumsum_p2(float* __restrict__ part)
{
  int b = blockIdx.x, d = threadIdx.x;
  float run = 0.f;
  for (int c = 0; c < 64; ++c) {
    float v = part[(b * 64 + c) * 128 + d];
    part[(b * 64 + c) * 128 + d] = run;
    run += v;
  }
}

// ---------------------------------------------------------------------------
extern "C" void kernel_launch(void* const* d_in, const int* in_sizes, int n_in,
                              void* d_out, int out_size, void* d_ws, size_t ws_size,
                              hipStream_t stream)
{
  const float* x       = (const float*)d_in[0];
  const float* pW      = (const float*)d_in[1];
  const float* pb      = (const float*)d_in[2];
  const float* cW      = (const float*)d_in[3];
  const float* cb      = (const float*)d_in[4];
  const float* aW      = (const float*)d_in[5];
  const float* ab      = (const float*)d_in[6];
  const float* uW      = (const float*)d_in[7];
  const float* ub      = (const float*)d_in[8];
  const float* eW      = (const float*)d_in[9];
  const float* eb      = (const float*)d_in[10];
  const float* la_win  = (const float*)d_in[11];
  const float* la_bin  = (const float*)d_in[12];
  const float* la_wout = (const float*)d_in[13];
  const float* la_bout = (const float*)d_in[14];
  const float* beW     = (const float*)d_in[15];
  const float* beb     = (const float*)d_in[16];
  const float* ba_win  = (const float*)d_in[17];
  const float* ba_bin  = (const float*)d_in[18];
  const float* ba_wout = (const float*)d_in[19];
  const float* ba_bout = (const float*)d_in[20];
  const float* bpW     = (const float*)d_in[21];
  const float* bpb     = (const float*)d_in[22];

  float* ws   = (float*)d_ws;
  float* outF = (float*)d_out;

  uint16_t* WB  = (uint16_t*)ws;
  float* base   = ws + 344064;
  uint16_t* featsB = (uint16_t*)base;
  float* csumB  = base;
  float* partB  = base + 2097152;
  uint16_t* eB  = (uint16_t*)(base + 4194304);   // e0 / b0
  uint16_t* projB = (uint16_t*)(base + 5242880);
  uint16_t* VtbB  = (uint16_t*)(base + 8388608);
  float* OpartB = base + 9437184;
  float* mlB    = base + 15728640;

  // 0. weights -> bf16
  WPtrs wp;
  wp.p[0] = pW; wp.p[1] = cW; wp.p[2] = aW; wp.p[3] = uW; wp.p[4] = eW;
  wp.p[5] = la_win; wp.p[6] = la_wout; wp.p[7] = beW; wp.p[8] = ba_win; wp.p[9] = ba_wout;
  pack_weights<<<dim3(672), 256, 0, stream>>>(wp, WB);

  // 1. feats = relu(segment linears) -> bf16
  gemm_feats64<<<dim3(256, 4), 256, 0, stream>>>(x, WB, pb, cb, ab, ub, featsB);
  // 2. e0 = relu(feats @ eW^T + eb) -> bf16, remapped (B,S)->(S,B)
  gemm64<true, true, true, true><<<dim3(256, 1), 256, 0, stream>>>(
      featsB, 512, WB + OFF_EW, eb, eB, 128, 16384, 512);
  // 3. proj1 = e0 @ la_win^T + la_bin -> bf16
  gemm64<true, true, false, false><<<dim3(256, 3), 256, 0, stream>>>(
      eB, 128, WB + OFF_LAWIN, la_bin, projB, 384, 16384, 128);
  // 4. V pack + 3-split flash
  vpack<<<dim3(32, 8), 256, 0, stream>>>(projB, VtbB, 2048);
  attn_split3<<<dim3(32, 8, 3), 256, 0, stream>>>(projB, VtbB, OpartB, mlB, 2048);
  // 5. e = combine(att1) @ la_wout^T + la_bout -> d_out (fp32), combine inlined
  gemm_attc64<false><<<dim3(256), 256, 0, stream>>>(
      OpartB, mlB, WB + OFF_LAWOUT, la_bout, nullptr, nullptr, outF, 16384);
  // 6-7. csum (local prefixes + chunk offsets; p3 fused into becat)
  cumsum_p1<<<dim3(64, 8), 128, 0, stream>>>(outF, csumB, partB);
  cumsum_p2<<<dim3(8), 128, 0, stream>>>(partB);
  // 8. b0 = relu(cat(left,right) @ beW^T + beb) -> bf16
  gemm_becat64<<<dim3(256), 256, 0, stream>>>(csumB, partB, WB + OFF_BEW, beb, eB);
  // 9. proj2
  gemm64<true, true, false, false><<<dim3(256, 3), 256, 0, stream>>>(
      eB, 128, WB + OFF_BAWIN, ba_bin, projB, 384, 16376, 128);
  // 10. V pack + att2 (Slen = 2047)
  vpack<<<dim3(32, 8), 256, 0, stream>>>(projB, VtbB, 2047);
  attn_split3<<<dim3(32, 8, 3), 256, 0, stream>>>(projB, VtbB, OpartB, mlB, 2047);
  // 11. bout GEMM: combine inlined + fused sigmoid head -> d_out tail
  gemm_attc64<true><<<dim3(256), 256, 0, stream>>>(
      OpartB, mlB, WB + OFF_BAWOUT, ba_bout, bpW, bpb, outF + 2097152, 16376);
}